// Round 12
// baseline (381.640 us; speedup 1.0000x reference)
//
#include <hip/hip_runtime.h>
#include <hip/hip_bf16.h>

#define NNODES 100000
#define NEDGES 1600000
#define NEG_SLOPE 0.2f

#define CHUNK 4096
#define EPT 16                                  // edges per thread in k_lsort
#define NBLK ((NEDGES + CHUNK - 1) / CHUNK)     // 391 sort blocks
#define NB ((NNODES + 255) / 256)               // 391 buckets (256 nodes each)
#define FLATN (NB * NBLK)                       // 152881
#define SCB ((FLATN + 255) / 256)               // 598
#define FCAP 5632                               // bucket entry cap (mean 4092, +24 sigma)

typedef __attribute__((ext_vector_type(8))) short bf16x8;
typedef __attribute__((ext_vector_type(4))) float f32x4;
typedef __attribute__((ext_vector_type(2))) float f32x2;

// CDNA packed fp32 (dual-issue) via VOP3P — compiler does not auto-form these.
__device__ __forceinline__ f32x2 pk_fma(f32x2 a, f32x2 b, f32x2 c) {
    f32x2 d;
    asm("v_pk_fma_f32 %0, %1, %2, %3" : "=v"(d) : "v"(a), "v"(b), "v"(c));
    return d;
}
__device__ __forceinline__ f32x2 pk_add(f32x2 a, f32x2 b) {
    f32x2 d;
    asm("v_pk_add_f32 %0, %1, %2" : "=v"(d) : "v"(a), "v"(b));
    return d;
}
__device__ __forceinline__ f32x2 pk_mul(f32x2 a, f32x2 b) {
    f32x2 d;
    asm("v_pk_mul_f32 %0, %1, %2" : "=v"(d) : "v"(a), "v"(b));
    return d;
}
__device__ __forceinline__ f32x2 pk_abs(f32x2 a) {
    f32x2 r;
    r.x = __uint_as_float(__float_as_uint(a.x) & 0x7FFFFFFFu);
    r.y = __uint_as_float(__float_as_uint(a.y) & 0x7FFFFFFFu);
    return r;
}

__device__ __forceinline__ float wave_sum64(float v) {
#pragma unroll
    for (int off = 1; off < 64; off <<= 1) v += __shfl_xor(v, off, 64);
    return v;
}

__device__ __forceinline__ int wave_sum64i(int v) {
#pragma unroll
    for (int off = 1; off < 64; off <<= 1) v += __shfl_xor(v, off, 64);
    return v;
}

// f32 -> bf16 (RNE)
__device__ __forceinline__ unsigned short bf16rne(float a) {
    unsigned u = __float_as_uint(a);
    return (unsigned short)((u + 0x7FFFu + ((u >> 16) & 1u)) >> 16);
}

// pack two f32 -> one uint of 2 bf16 (RNE); low ushort = a
__device__ __forceinline__ unsigned pack_bf2(float a, float b) {
    unsigned ua = __float_as_uint(a), ub = __float_as_uint(b);
    ua = (ua + 0x7FFFu + ((ua >> 16) & 1u)) >> 16;
    ub = (ub + 0x7FFFu + ((ub >> 16) & 1u));
    return ua | (ub & 0xFFFF0000u);
}

// one uint of 2 packed bf16 -> f32x2 {lo, hi}
__device__ __forceinline__ f32x2 up2(unsigned u) {
    f32x2 r;
    r.x = __uint_as_float(u << 16);
    r.y = __uint_as_float(u & 0xFFFF0000u);
    return r;
}

// ---------------- phase A: per-chunk counting sort by bucket (all-coalesced) ----------------

__global__ __launch_bounds__(256) void k_lsort(const int* __restrict__ src,
                                               const int* __restrict__ dst,
                                               const float* __restrict__ ea,
                                               uint2* __restrict__ tmps,
                                               int* __restrict__ gcnt,
                                               int* __restrict__ lscan,
                                               float* __restrict__ easum) {
    __shared__ uint2 ent[CHUNK];                 // 32 KB
    __shared__ unsigned short perm[CHUNK];       // 8 KB
    __shared__ int hist[NB];
    __shared__ int cur[NB];
    __shared__ float ws[4];
    const int t = threadIdx.x;
    const int j = blockIdx.x;
    const int base = j * CHUNK;
    const int n = min(CHUNK, NEDGES - base);

    for (int b = t; b < NB; b += 256) hist[b] = 0;
    __syncthreads();

    int bkt[EPT];
    float s = 0.f;
#pragma unroll
    for (int k = 0; k < EPT; ++k) {
        const int l = t + k * 256;
        bkt[k] = -1;
        if (l < n) {
            const int i = base + l;
            const int d = dst[i];
            const float e = ea[i];
            const int b = d >> 8;
            bkt[k] = b;
            ent[l] = make_uint2((unsigned)src[i] | ((unsigned)(d & 255) << 17),
                                __float_as_uint(e));
            atomicAdd(&hist[b], 1);
            s += e;
        }
    }
    s = wave_sum64(s);
    if ((t & 63) == 0) ws[t >> 6] = s;
    __syncthreads();
    if (t == 0) atomicAdd(easum, ws[0] + ws[1] + ws[2] + ws[3]);

    // exclusive scan of hist[0..NB) -> cur, wave 0 only (56 lanes x 7 elems)
    if (t < 64) {
        int x[7];
        int run = 0;
#pragma unroll
        for (int q = 0; q < 7; ++q) {
            const int idx = t * 7 + q;
            x[q] = (idx < NB) ? hist[idx] : 0;
            run += x[q];
        }
        int inc = run;
#pragma unroll
        for (int o = 1; o < 64; o <<= 1) {
            int u = __shfl_up(inc, o, 64);
            if (t >= o) inc += u;
        }
        int r = inc - run;   // lane-exclusive
#pragma unroll
        for (int q = 0; q < 7; ++q) {
            const int idx = t * 7 + q;
            if (idx < NB) cur[idx] = r;
            r += x[q];
        }
    }
    __syncthreads();

#pragma unroll
    for (int k = 0; k < EPT; ++k) {
        if (bkt[k] >= 0) {
            const int r = atomicAdd(&cur[bkt[k]], 1);
            perm[r] = (unsigned short)(t + k * 256);
        }
    }
    __syncthreads();

    for (int o = t; o < n; o += 256)
        tmps[base + o] = ent[perm[o]];           // coalesced global write
    for (int b = t; b < NB; b += 256) {
        gcnt[b * NBLK + j] = hist[b];            // bucket-major (for flat scan)
        lscan[j * NB + b] = cur[b] - hist[b];    // local exclusive offset
    }
}

// ---------------- flat exclusive scan of gcnt[FLATN] -> goff ----------------

__global__ __launch_bounds__(256) void k_part2(const int* __restrict__ v, int n,
                                               int* __restrict__ bsum) {
    int i = blockIdx.x * 256 + threadIdx.x;
    int x = (i < n) ? v[i] : 0;
    x = wave_sum64i(x);
    __shared__ int wsh[4];
    if ((threadIdx.x & 63) == 0) wsh[threadIdx.x >> 6] = x;
    __syncthreads();
    if (threadIdx.x == 0) bsum[blockIdx.x] = wsh[0] + wsh[1] + wsh[2] + wsh[3];
}

__global__ __launch_bounds__(1024) void k_scanb2(const int* __restrict__ bsum, int nb,
                                                 int* __restrict__ boff,
                                                 int* __restrict__ rowptr) {
    __shared__ int sh[1024];
    int t = threadIdx.x;
    int v = (t < nb) ? bsum[t] : 0;
    sh[t] = v;
    __syncthreads();
    for (int off = 1; off < 1024; off <<= 1) {
        int u = (t >= off) ? sh[t - off] : 0;
        __syncthreads();
        sh[t] += u;
        __syncthreads();
    }
    if (t < nb) boff[t] = sh[t] - v;
    if (t == 0) rowptr[NNODES] = NEDGES;
}

__global__ __launch_bounds__(256) void k_scanfin2(const int* __restrict__ v, int n,
                                                  const int* __restrict__ boff,
                                                  int* __restrict__ out) {
    int t = threadIdx.x, lane = t & 63, wave = t >> 6;
    int i = blockIdx.x * 256 + t;
    int x = (i < n) ? v[i] : 0;
    int orig = x;
#pragma unroll
    for (int off = 1; off < 64; off <<= 1) {
        int u = __shfl_up(x, off, 64);
        if (lane >= off) x += u;
    }
    __shared__ int wsh[4];
    if (lane == 63) wsh[wave] = x;
    __syncthreads();
    int wexc = 0;
    for (int w = 0; w < wave; ++w) wexc += wsh[w];
    if (i < n) out[i] = boff[blockIdx.x] + wexc + x - orig;
}

// ---------------- phase C: per-bucket gather + LDS counting sort by node ----------------

__global__ __launch_bounds__(256) void k_fsort(const uint2* __restrict__ tmps,
                                               const int* __restrict__ lscan,
                                               const int* __restrict__ goff,
                                               int* __restrict__ rowptr,
                                               uint2* __restrict__ edata) {
    __shared__ uint2 ent[FCAP];                  // 44 KB
    __shared__ unsigned short perm[FCAP];        // 11 KB
    __shared__ int joff[NBLK + 1];
    __shared__ int jsrc[NBLK];
    __shared__ int hist[256];
    __shared__ int cur[256];
    const int b = blockIdx.x;
    const int t = threadIdx.x;
    const int base = goff[b * NBLK];             // bucket base position in edata

    for (int q = t; q < 256; q += 256) hist[q] = 0;
    for (int j = t; j < NBLK; j += 256) {
        joff[j] = goff[b * NBLK + j] - base;
        jsrc[j] = j * CHUNK + lscan[j * NB + b];
    }
    if (t == 0) joff[NBLK] = ((b == NB - 1) ? NEDGES : goff[(b + 1) * NBLK]) - base;
    __syncthreads();
    const int T = min(joff[NBLK], FCAP);

    for (int idx = t; idx < T; idx += 256) {
        int lo = 0, hi = NBLK;
        while (hi - lo > 1) { int mid = (lo + hi) >> 1; if (joff[mid] <= idx) lo = mid; else hi = mid; }
        const uint2 e = tmps[jsrc[lo] + (idx - joff[lo])];   // piecewise-coalesced
        ent[idx] = e;
        atomicAdd(&hist[(e.x >> 17) & 255u], 1);
    }
    __syncthreads();

    // exclusive scan hist[0..256) -> cur, wave 0 (64 lanes x 4)
    if (t < 64) {
        int x[4];
        int run = 0;
#pragma unroll
        for (int q = 0; q < 4; ++q) { x[q] = hist[t * 4 + q]; run += x[q]; }
        int inc = run;
#pragma unroll
        for (int o = 1; o < 64; o <<= 1) {
            int u = __shfl_up(inc, o, 64);
            if (t >= o) inc += u;
        }
        int r = inc - run;
#pragma unroll
        for (int q = 0; q < 4; ++q) { cur[t * 4 + q] = r; r += x[q]; }
    }
    __syncthreads();

    {
        const int i = b * 256 + t;
        if (i < NNODES) rowptr[i] = base + cur[t];
    }
    __syncthreads();    // rowptr reads of cur must complete before rank mutation

    for (int idx = t; idx < T; idx += 256) {
        const int d = (int)((ent[idx].x >> 17) & 255u);
        const int r = atomicAdd(&cur[d], 1);
        perm[r] = (unsigned short)idx;
    }
    __syncthreads();
    for (int k = t; k < T; k += 256)
        edata[base + k] = ent[perm[k]];          // coalesced global write
}

// ---------------- weight pre-conversion: f32 [K][64] x2 -> bf16 col-major [128][K] ----------------

__global__ __launch_bounds__(256) void k_wprep(const float* __restrict__ W1l, const float* __restrict__ W1r,
                                               const float* __restrict__ W2l, const float* __restrict__ W2r,
                                               const float* __restrict__ W3l, const float* __restrict__ W3r,
                                               unsigned short* __restrict__ Wt1,
                                               unsigned short* __restrict__ Wt2,
                                               unsigned short* __restrict__ Wt3) {
    const int idx = blockIdx.x * 256 + threadIdx.x;
    if (idx < 16384) {                            // Wt1: 128 cols x 128 k
        const int c = idx >> 7, k = idx & 127;
        const float v = (c < 64) ? W1l[k * 64 + c] : W1r[k * 64 + (c - 64)];
        Wt1[c * 128 + k] = bf16rne(v);
    } else if (idx < 24576) {                     // Wt2: 128 cols x 64 k
        const int j = idx - 16384;
        const int c = j >> 6, k = j & 63;
        const float v = (c < 64) ? W2l[k * 64 + c] : W2r[k * 64 + (c - 64)];
        Wt2[c * 64 + k] = bf16rne(v);
    } else if (idx < 32768) {                     // Wt3: 128 cols x 64 k
        const int j = idx - 24576;
        const int c = j >> 6, k = j & 63;
        const float v = (c < 64) ? W3l[k * 64 + c] : W3r[k * 64 + (c - 64)];
        Wt3[c * 64 + k] = bf16rne(v);
    }
}

// ---------------- MFMA dual GEMM: [XL|XR] = X @ [Wl|Wr] + bias, bf16 in/out ----------------
// Block = 64 rows x 128 cols, full K in LDS. mfma_f32_16x16x32_bf16 fragments:
// A: row=lane&15, k=(lane>>4)*8+j; B: col=lane&15, k=(lane>>4)*8+j;
// D: col=lane&15, row=(lane>>4)*4+reg. Row pad +8 bf16 -> 2-way (free) LDS banks.
// W pre-converted bf16 col-major (k_wprep) -> staging is pure uint4 copies.

template <int K, bool F32IN>
__global__ __launch_bounds__(256) void k_gemm_mfma(const void* __restrict__ Xin,
                                                   const unsigned short* __restrict__ Wt,
                                                   const float* __restrict__ bl,
                                                   const float* __restrict__ br,
                                                   unsigned short* __restrict__ XLu,
                                                   unsigned short* __restrict__ XRu) {
    constexpr int KP = K + 8;
    __shared__ unsigned short sA[64 * KP];
    __shared__ unsigned short sB[128 * KP];
    const int t = threadIdx.x;
    const int w = t >> 6, lane = t & 63;
    const int r0 = blockIdx.x * 64;

    // stage B: pure vector copy of pre-converted weights
    {
        const uint4* Wu = (const uint4*)Wt;
#pragma unroll
        for (int idx = t; idx < 128 * (K / 8); idx += 256) {
            const int row = idx / (K / 8), q = idx % (K / 8);
            *(uint4*)&sB[row * KP + q * 8] = Wu[idx];
        }
    }
    // stage A: 64 rows x K
    if constexpr (F32IN) {
        const float* X = (const float*)Xin;
        for (int idx = t; idx < 64 * (K / 4); idx += 256) {
            const int row = idx / (K / 4), q = idx % (K / 4);
            const int rr = min(r0 + row, NNODES - 1);
            const float4 v = *(const float4*)&X[(size_t)rr * K + q * 4];
            unsigned* p = (unsigned*)&sA[row * KP + q * 4];
            p[0] = pack_bf2(v.x, v.y);
            p[1] = pack_bf2(v.z, v.w);
        }
    } else {
        const uint4* X = (const uint4*)Xin;      // packed bf16 rows: 8 x uint4
        for (int idx = t; idx < 64 * 8; idx += 256) {
            const int row = idx >> 3, q = idx & 7;
            const int rr = min(r0 + row, NNODES - 1);
            *(uint4*)&sA[row * KP + q * 8] = X[(size_t)rr * 8 + q];
        }
    }
    __syncthreads();

    f32x4 acc[8] = {};
    const int mrow = w * 16 + (lane & 15);
    const int kb = (lane >> 4) * 8;
#pragma unroll
    for (int kc = 0; kc < K / 32; ++kc) {
        const bf16x8 af = *(const bf16x8*)&sA[mrow * KP + kc * 32 + kb];
#pragma unroll
        for (int nt = 0; nt < 8; ++nt) {
            const bf16x8 bfr = *(const bf16x8*)&sB[(nt * 16 + (lane & 15)) * KP + kc * 32 + kb];
            acc[nt] = __builtin_amdgcn_mfma_f32_16x16x32_bf16(af, bfr, acc[nt], 0, 0, 0);
        }
    }

    // epilogue: bias + bf16 store
    const int colL = lane & 15;
    const int rbase = r0 + w * 16 + (lane >> 4) * 4;
#pragma unroll
    for (int nt = 0; nt < 8; ++nt) {
        const int col = nt * 16 + colL;
        const bool isL = col < 64;
        const float bv = isL ? bl[col] : br[col - 64];
        unsigned short* OUT = isL ? XLu : XRu;
        const int oc = isL ? col : col - 64;
#pragma unroll
        for (int r = 0; r < 4; ++r) {
            const int grow = rbase + r;
            if (grow < NNODES)
                OUT[(size_t)grow * 64 + oc] = bf16rne(acc[nt][r] + bv);
        }
    }
}

// ---------------- fused GATv2 edge pass (packed-f32 math) ----------------
// One wave per node. lane = 8*group + fl; group g handles edge e+g (8/batch);
// lane holds features [fl*8, fl*8+8) as 4x f32x2 from one uint4 of packed bf16.
// Inner math uses v_pk_fma_f32 (dual f32/instr). Fused leaky:
// att*leaky(m) = 0.6*(att.m) + 0.4*(att.|m|). Per-wave LDS combine, no barrier.

__global__ __launch_bounds__(256) void k_edge(const uint4* __restrict__ XLh,
                                              const uint4* __restrict__ XRh,
                                              const int* __restrict__ rowptr,
                                              const uint2* __restrict__ edata,
                                              const float* __restrict__ We,
                                              const float* __restrict__ att,
                                              const float* __restrict__ bias,
                                              const float* __restrict__ easum,
                                              unsigned* __restrict__ Hh) {
    __shared__ float red[4][8][65];              // bank = (g + 8*fl + k) % 32: 2/bank (free)
    const int wave = threadIdx.x >> 6, lane = threadIdx.x & 63;
    const int g = lane >> 3, fl = lane & 7;
    const int fo = fl * 8;
    f32x2 We2[4], att2[4], xr2[4], xl2[4], acc2[4];
#pragma unroll
    for (int k = 0; k < 4; ++k) {
        We2[k] = *(const f32x2*)&We[fo + 2 * k];
        att2[k] = *(const f32x2*)&att[fo + 2 * k];
    }
    const float bias_l = bias[lane];
    const float ea_mean = easum[0] * (1.0f / NEDGES);

    const int i = blockIdx.x * 4 + wave;         // exact grid: always < NNODES

    {
        const uint4 wr = XRh[(size_t)i * 8 + fl];
        xr2[0] = up2(wr.x); xr2[1] = up2(wr.y); xr2[2] = up2(wr.z); xr2[3] = up2(wr.w);
        const uint4 wl = XLh[(size_t)i * 8 + fl];
        xl2[0] = up2(wl.x); xl2[1] = up2(wl.y); xl2[2] = up2(wl.z); xl2[3] = up2(wl.w);
    }

    // self-loop (src=i, ea=ea_mean): wave-uniform logit
    {
        f32x2 em; em.x = ea_mean; em.y = ea_mean;
        f32x2 s1 = {0.f, 0.f}, s2 = {0.f, 0.f};
#pragma unroll
        for (int k = 0; k < 4; ++k) {
            const f32x2 m = pk_add(pk_fma(em, We2[k], xr2[k]), xl2[k]);
            s1 = pk_fma(att2[k], m, s1);
            s2 = pk_fma(att2[k], pk_abs(m), s2);
        }
        float pt = fmaf(0.6f, s1.x + s1.y, 0.4f * (s2.x + s2.y));
        pt += __shfl_xor(pt, 1);
        pt += __shfl_xor(pt, 2);
        pt += __shfl_xor(pt, 4);
        red[wave][0][64] = pt;                   // spare slot broadcast
    }
    float M = red[wave][0][64];
    __builtin_amdgcn_wave_barrier();
    float S = (g == 0) ? 1.f : 0.f;              // per-group partial denominator
#pragma unroll
    for (int k = 0; k < 4; ++k) {
        acc2[k].x = (g == 0) ? xl2[k].x : 0.f;
        acc2[k].y = (g == 0) ? xl2[k].y : 0.f;
    }

    const int e0 = rowptr[i];
    const int ne = rowptr[i + 1] - e0;
    const uint2 z2 = make_uint2(0u, 0u);

    uint2 se = (g < ne) ? edata[e0 + g] : z2;    // meta prefetch, 1 batch ahead
    for (int e = 0; e < ne; e += 8) {
        const uint2 se_cur = se;
        const bool valid = (e + g) < ne;
        if (e + 8 + g < ne) se = edata[e0 + e + 8 + g];
        const int s = (int)(se_cur.x & 0x1FFFFu);
        const float eav = __uint_as_float(se_cur.y);
        f32x2 ev; ev.x = eav; ev.y = eav;
        const uint4 wv = XLh[(size_t)s * 8 + fl];
        f32x2 v2[4];
        v2[0] = up2(wv.x); v2[1] = up2(wv.y); v2[2] = up2(wv.z); v2[3] = up2(wv.w);

        f32x2 s1 = {0.f, 0.f}, s2 = {0.f, 0.f};
#pragma unroll
        for (int k = 0; k < 4; ++k) {
            const f32x2 m = pk_add(pk_fma(ev, We2[k], xr2[k]), v2[k]);
            s1 = pk_fma(att2[k], m, s1);
            s2 = pk_fma(att2[k], pk_abs(m), s2);
        }
        float d = fmaf(0.6f, s1.x + s1.y, 0.4f * (s2.x + s2.y));
        d += __shfl_xor(d, 1);
        d += __shfl_xor(d, 2);
        d += __shfl_xor(d, 4);                   // group-uniform logit
        const float a = valid ? d : -1e30f;

        if (__any(a > M)) {                      // ballot; wave-uniform branch
            float am = fmaxf(a, __shfl_xor(a, 8));
            am = fmaxf(am, __shfl_xor(am, 16));
            am = fmaxf(am, __shfl_xor(am, 32));
            const float sc = __expf(M - am);     // exact rescale
            f32x2 sc2; sc2.x = sc; sc2.y = sc;
            S *= sc;
#pragma unroll
            for (int k = 0; k < 4; ++k) acc2[k] = pk_mul(sc2, acc2[k]);
            M = am;
        }
        const float p = __expf(a - M);           // 0 for invalid groups
        S += p;                                  // group-partial (deferred reduce)
        f32x2 p2; p2.x = p; p2.y = p;
#pragma unroll
        for (int k = 0; k < 4; ++k) acc2[k] = pk_fma(p2, v2[k], acc2[k]);
    }

    // reduce S across groups (xor 8/16/32 touches g bits only)
    S += __shfl_xor(S, 8);
    S += __shfl_xor(S, 16);
    S += __shfl_xor(S, 32);

    // per-wave LDS transpose-combine (no inter-wave sharing -> no block barrier)
#pragma unroll
    for (int k = 0; k < 4; ++k) {
        red[wave][g][fo + 2 * k] = acc2[k].x;
        red[wave][g][fo + 2 * k + 1] = acc2[k].y;
    }
    asm volatile("" ::: "memory");
    __builtin_amdgcn_wave_barrier();             // DS ops complete in-order per wave
    float o = 0.f;
#pragma unroll
    for (int gg = 0; gg < 8; ++gg) o += red[wave][gg][lane];
    o = fmaxf(o / S + bias_l, 0.f);              // bias + fused ReLU
    const float on = __shfl_xor(o, 1);
    if (!(lane & 1))
        Hh[(size_t)i * 32 + (lane >> 1)] = pack_bf2(o, on);   // packed bf16 store
}

// ---------------- tail: mean pool + linear + softmax ----------------

__global__ __launch_bounds__(256) void k_colsum(const unsigned* __restrict__ Hh,
                                                float* __restrict__ gsum) {
    const int t = threadIdx.x;
    const int c = t & 31;                        // uint column = feature pair
    const int rl = t >> 5;                       // 0..7
    float s0 = 0.f, s1 = 0.f;
    for (int r = blockIdx.x * 8 + rl; r < NNODES; r += gridDim.x * 8) {
        const unsigned u = Hh[(size_t)r * 32 + c];
        s0 += __uint_as_float(u << 16);
        s1 += __uint_as_float(u & 0xFFFF0000u);
    }
    __shared__ float ls[8][64];
    ls[rl][2 * c] = s0;
    ls[rl][2 * c + 1] = s1;
    __syncthreads();
    if (t < 64) {
        float s = 0.f;
#pragma unroll
        for (int q = 0; q < 8; ++q) s += ls[q][t];
        atomicAdd(&gsum[t], s);
    }
}

__global__ __launch_bounds__(64) void k_head(const float* __restrict__ gsum,
                                             const float* __restrict__ Wlin,
                                             const float* __restrict__ blin,
                                             float* __restrict__ out) {
    int lane = threadIdx.x;
    float g = gsum[lane] * (1.0f / NNODES);
    float a0 = wave_sum64(g * Wlin[lane * 2 + 0]);
    float a1 = wave_sum64(g * Wlin[lane * 2 + 1]);
    if (lane == 0) {
        float l0 = a0 + blin[0], l1 = a1 + blin[1];
        float mx = fmaxf(l0, l1);
        float e0 = __expf(l0 - mx), e1 = __expf(l1 - mx);
        float inv = 1.f / (e0 + e1);
        out[0] = e0 * inv;
        out[1] = e1 * inv;
    }
}

extern "C" void kernel_launch(void* const* d_in, const int* in_sizes, int n_in,
                              void* d_out, int out_size, void* d_ws, size_t ws_size,
                              hipStream_t stream) {
    const float* x = (const float*)d_in[0];
    const int* ei = (const int*)d_in[1];
    const float* ea = (const float*)d_in[2];
    const int* src = ei;
    const int* dst = ei + NEDGES;
    auto W = [&](int i) { return (const float*)d_in[i]; };

    char* ws = (char*)d_ws;
    size_t off = 0;
    auto alloc = [&](size_t bytes) {
        void* p = ws + off;
        off += (bytes + 255) & ~(size_t)255;
        return p;
    };
    unsigned short* XLu = (unsigned short*)alloc((size_t)NNODES * 64 * 2);  // packed bf16
    unsigned short* XRu = (unsigned short*)alloc((size_t)NNODES * 64 * 2);  // packed bf16
    unsigned* Hh = (unsigned*)alloc((size_t)NBLK * CHUNK * 8);  // 12.82 MB: packed bf16 H, aliased by tmps
    int* rowptr = (int*)alloc((size_t)(NNODES + 1) * 4);
    uint2* edata = (uint2*)alloc((size_t)NEDGES * 8);
    float* easum = (float*)alloc(4);
    float* gsum = (float*)alloc(64 * 4);
    int* gcnt = (int*)alloc((size_t)FLATN * 4);
    int* lscan = (int*)alloc((size_t)FLATN * 4);
    int* goff = (int*)alloc((size_t)FLATN * 4);
    int* part2 = (int*)alloc((size_t)SCB * 4);
    int* boff2 = (int*)alloc((size_t)SCB * 4);
    unsigned short* Wt1 = (unsigned short*)alloc(16384 * 2);
    unsigned short* Wt2 = (unsigned short*)alloc(8192 * 2);
    unsigned short* Wt3 = (unsigned short*)alloc(8192 * 2);
    uint2* tmps = (uint2*)Hh;  // Hh dead until layer-1 k_edge; sort uses it first

    hipMemsetAsync(easum, 0, 4, stream);
    hipMemsetAsync(gsum, 0, 64 * 4, stream);

    k_wprep<<<128, 256, 0, stream>>>(W(3), W(5), W(10), W(12), W(17), W(19), Wt1, Wt2, Wt3);
    k_lsort<<<NBLK, 256, 0, stream>>>(src, dst, ea, tmps, gcnt, lscan, easum);
    k_part2<<<SCB, 256, 0, stream>>>(gcnt, FLATN, part2);
    k_scanb2<<<1, 1024, 0, stream>>>(part2, SCB, boff2, rowptr);
    k_scanfin2<<<SCB, 256, 0, stream>>>(gcnt, FLATN, boff2, goff);
    k_fsort<<<NB, 256, 0, stream>>>(tmps, lscan, goff, rowptr, edata);

    int gemm_grid = (NNODES + 63) / 64;   // 1563
    int edge_grid = NNODES / 4;           // exact: one wave per node

    k_gemm_mfma<128, true><<<gemm_grid, 256, 0, stream>>>(x, Wt1, W(4), W(6), XLu, XRu);
    k_edge<<<edge_grid, 256, 0, stream>>>((const uint4*)XLu, (const uint4*)XRu, rowptr, edata,
                                          W(7), W(8), W(9), easum, Hh);
    k_gemm_mfma<64, false><<<gemm_grid, 256, 0, stream>>>(Hh, Wt2, W(11), W(13), XLu, XRu);
    k_edge<<<edge_grid, 256, 0, stream>>>((const uint4*)XLu, (const uint4*)XRu, rowptr, edata,
                                          W(14), W(15), W(16), easum, Hh);
    k_gemm_mfma<64, false><<<gemm_grid, 256, 0, stream>>>(Hh, Wt3, W(18), W(20), XLu, XRu);
    k_edge<<<edge_grid, 256, 0, stream>>>((const uint4*)XLu, (const uint4*)XRu, rowptr, edata,
                                          W(21), W(22), W(23), easum, Hh);

    k_colsum<<<256, 256, 0, stream>>>(Hh, gsum);
    k_head<<<1, 64, 0, stream>>>(gsum, W(24), W(25), (float*)d_out);
}

// Round 13
// 346.666 us; speedup vs baseline: 1.1009x; 1.1009x over previous
//
#include <hip/hip_runtime.h>
#include <hip/hip_bf16.h>

#define NNODES 100000
#define NEDGES 1600000
#define NEG_SLOPE 0.2f

#define CHUNK 4096
#define EPT 16                                  // edges per thread in k_lsort
#define NBLK ((NEDGES + CHUNK - 1) / CHUNK)     // 391 sort blocks
#define NB ((NNODES + 255) / 256)               // 391 buckets (256 nodes each)
#define FLATN (NB * NBLK)                       // 152881
#define SCB ((FLATN + 255) / 256)               // 598
#define FCAP 5632                               // bucket entry cap (mean 4092, +24 sigma)

typedef __attribute__((ext_vector_type(8))) short bf16x8;
typedef __attribute__((ext_vector_type(4))) float f32x4;

__device__ __forceinline__ float wave_sum64(float v) {
#pragma unroll
    for (int off = 1; off < 64; off <<= 1) v += __shfl_xor(v, off, 64);
    return v;
}

__device__ __forceinline__ int wave_sum64i(int v) {
#pragma unroll
    for (int off = 1; off < 64; off <<= 1) v += __shfl_xor(v, off, 64);
    return v;
}

// f32 -> bf16 (RNE)
__device__ __forceinline__ unsigned short bf16rne(float a) {
    unsigned u = __float_as_uint(a);
    return (unsigned short)((u + 0x7FFFu + ((u >> 16) & 1u)) >> 16);
}

// pack two f32 -> one uint of 2 bf16 (RNE); low ushort = a
__device__ __forceinline__ unsigned pack_bf2(float a, float b) {
    unsigned ua = __float_as_uint(a), ub = __float_as_uint(b);
    ua = (ua + 0x7FFFu + ((ua >> 16) & 1u)) >> 16;
    ub = (ub + 0x7FFFu + ((ub >> 16) & 1u));
    return ua | (ub & 0xFFFF0000u);
}

__device__ __forceinline__ void unpack_bf8(uint4 w, float* f) {
    f[0] = __uint_as_float(w.x << 16);
    f[1] = __uint_as_float(w.x & 0xFFFF0000u);
    f[2] = __uint_as_float(w.y << 16);
    f[3] = __uint_as_float(w.y & 0xFFFF0000u);
    f[4] = __uint_as_float(w.z << 16);
    f[5] = __uint_as_float(w.z & 0xFFFF0000u);
    f[6] = __uint_as_float(w.w << 16);
    f[7] = __uint_as_float(w.w & 0xFFFF0000u);
}

// ---------------- phase A: per-chunk counting sort by bucket (all-coalesced) ----------------

__global__ __launch_bounds__(256) void k_lsort(const int* __restrict__ src,
                                               const int* __restrict__ dst,
                                               const float* __restrict__ ea,
                                               uint2* __restrict__ tmps,
                                               int* __restrict__ gcnt,
                                               int* __restrict__ lscan,
                                               float* __restrict__ easum) {
    __shared__ uint2 ent[CHUNK];                 // 32 KB
    __shared__ unsigned short perm[CHUNK];       // 8 KB
    __shared__ int hist[NB];
    __shared__ int cur[NB];
    __shared__ float ws[4];
    const int t = threadIdx.x;
    const int j = blockIdx.x;
    const int base = j * CHUNK;
    const int n = min(CHUNK, NEDGES - base);

    for (int b = t; b < NB; b += 256) hist[b] = 0;
    __syncthreads();

    int bkt[EPT];
    float s = 0.f;
#pragma unroll
    for (int k = 0; k < EPT; ++k) {
        const int l = t + k * 256;
        bkt[k] = -1;
        if (l < n) {
            const int i = base + l;
            const int d = dst[i];
            const float e = ea[i];
            const int b = d >> 8;
            bkt[k] = b;
            ent[l] = make_uint2((unsigned)src[i] | ((unsigned)(d & 255) << 17),
                                __float_as_uint(e));
            atomicAdd(&hist[b], 1);
            s += e;
        }
    }
    s = wave_sum64(s);
    if ((t & 63) == 0) ws[t >> 6] = s;
    __syncthreads();
    if (t == 0) atomicAdd(easum, ws[0] + ws[1] + ws[2] + ws[3]);

    // exclusive scan of hist[0..NB) -> cur, wave 0 only (56 lanes x 7 elems)
    if (t < 64) {
        int x[7];
        int run = 0;
#pragma unroll
        for (int q = 0; q < 7; ++q) {
            const int idx = t * 7 + q;
            x[q] = (idx < NB) ? hist[idx] : 0;
            run += x[q];
        }
        int inc = run;
#pragma unroll
        for (int o = 1; o < 64; o <<= 1) {
            int u = __shfl_up(inc, o, 64);
            if (t >= o) inc += u;
        }
        int r = inc - run;   // lane-exclusive
#pragma unroll
        for (int q = 0; q < 7; ++q) {
            const int idx = t * 7 + q;
            if (idx < NB) cur[idx] = r;
            r += x[q];
        }
    }
    __syncthreads();

#pragma unroll
    for (int k = 0; k < EPT; ++k) {
        if (bkt[k] >= 0) {
            const int r = atomicAdd(&cur[bkt[k]], 1);
            perm[r] = (unsigned short)(t + k * 256);
        }
    }
    __syncthreads();

    for (int o = t; o < n; o += 256)
        tmps[base + o] = ent[perm[o]];           // coalesced global write
    for (int b = t; b < NB; b += 256) {
        gcnt[b * NBLK + j] = hist[b];            // bucket-major (for flat scan)
        lscan[j * NB + b] = cur[b] - hist[b];    // local exclusive offset
    }
}

// ---------------- flat exclusive scan of gcnt[FLATN] -> goff ----------------

__global__ __launch_bounds__(256) void k_part2(const int* __restrict__ v, int n,
                                               int* __restrict__ bsum) {
    int i = blockIdx.x * 256 + threadIdx.x;
    int x = (i < n) ? v[i] : 0;
    x = wave_sum64i(x);
    __shared__ int wsh[4];
    if ((threadIdx.x & 63) == 0) wsh[threadIdx.x >> 6] = x;
    __syncthreads();
    if (threadIdx.x == 0) bsum[blockIdx.x] = wsh[0] + wsh[1] + wsh[2] + wsh[3];
}

__global__ __launch_bounds__(1024) void k_scanb2(const int* __restrict__ bsum, int nb,
                                                 int* __restrict__ boff,
                                                 int* __restrict__ rowptr) {
    __shared__ int sh[1024];
    int t = threadIdx.x;
    int v = (t < nb) ? bsum[t] : 0;
    sh[t] = v;
    __syncthreads();
    for (int off = 1; off < 1024; off <<= 1) {
        int u = (t >= off) ? sh[t - off] : 0;
        __syncthreads();
        sh[t] += u;
        __syncthreads();
    }
    if (t < nb) boff[t] = sh[t] - v;
    if (t == 0) rowptr[NNODES] = NEDGES;
}

__global__ __launch_bounds__(256) void k_scanfin2(const int* __restrict__ v, int n,
                                                  const int* __restrict__ boff,
                                                  int* __restrict__ out) {
    int t = threadIdx.x, lane = t & 63, wave = t >> 6;
    int i = blockIdx.x * 256 + t;
    int x = (i < n) ? v[i] : 0;
    int orig = x;
#pragma unroll
    for (int off = 1; off < 64; off <<= 1) {
        int u = __shfl_up(x, off, 64);
        if (lane >= off) x += u;
    }
    __shared__ int wsh[4];
    if (lane == 63) wsh[wave] = x;
    __syncthreads();
    int wexc = 0;
    for (int w = 0; w < wave; ++w) wexc += wsh[w];
    if (i < n) out[i] = boff[blockIdx.x] + wexc + x - orig;
}

// ---------------- phase C: per-bucket gather + LDS counting sort by node ----------------

__global__ __launch_bounds__(256) void k_fsort(const uint2* __restrict__ tmps,
                                               const int* __restrict__ lscan,
                                               const int* __restrict__ goff,
                                               int* __restrict__ rowptr,
                                               uint2* __restrict__ edata) {
    __shared__ uint2 ent[FCAP];                  // 44 KB
    __shared__ unsigned short perm[FCAP];        // 11 KB
    __shared__ int joff[NBLK + 1];
    __shared__ int jsrc[NBLK];
    __shared__ int hist[256];
    __shared__ int cur[256];
    const int b = blockIdx.x;
    const int t = threadIdx.x;
    const int base = goff[b * NBLK];             // bucket base position in edata

    for (int q = t; q < 256; q += 256) hist[q] = 0;
    for (int j = t; j < NBLK; j += 256) {
        joff[j] = goff[b * NBLK + j] - base;
        jsrc[j] = j * CHUNK + lscan[j * NB + b];
    }
    if (t == 0) joff[NBLK] = ((b == NB - 1) ? NEDGES : goff[(b + 1) * NBLK]) - base;
    __syncthreads();
    const int T = min(joff[NBLK], FCAP);

    for (int idx = t; idx < T; idx += 256) {
        int lo = 0, hi = NBLK;
        while (hi - lo > 1) { int mid = (lo + hi) >> 1; if (joff[mid] <= idx) lo = mid; else hi = mid; }
        const uint2 e = tmps[jsrc[lo] + (idx - joff[lo])];   // piecewise-coalesced
        ent[idx] = e;
        atomicAdd(&hist[(e.x >> 17) & 255u], 1);
    }
    __syncthreads();

    // exclusive scan hist[0..256) -> cur, wave 0 (64 lanes x 4)
    if (t < 64) {
        int x[4];
        int run = 0;
#pragma unroll
        for (int q = 0; q < 4; ++q) { x[q] = hist[t * 4 + q]; run += x[q]; }
        int inc = run;
#pragma unroll
        for (int o = 1; o < 64; o <<= 1) {
            int u = __shfl_up(inc, o, 64);
            if (t >= o) inc += u;
        }
        int r = inc - run;
#pragma unroll
        for (int q = 0; q < 4; ++q) { cur[t * 4 + q] = r; r += x[q]; }
    }
    __syncthreads();

    {
        const int i = b * 256 + t;
        if (i < NNODES) rowptr[i] = base + cur[t];
    }
    __syncthreads();    // rowptr reads of cur must complete before rank mutation

    for (int idx = t; idx < T; idx += 256) {
        const int d = (int)((ent[idx].x >> 17) & 255u);
        const int r = atomicAdd(&cur[d], 1);
        perm[r] = (unsigned short)idx;
    }
    __syncthreads();
    for (int k = t; k < T; k += 256)
        edata[base + k] = ent[perm[k]];          // coalesced global write
}

// ---------------- weight pre-conversion: f32 [K][64] x2 -> bf16 col-major [128][K] ----------------

__global__ __launch_bounds__(256) void k_wprep(const float* __restrict__ W1l, const float* __restrict__ W1r,
                                               const float* __restrict__ W2l, const float* __restrict__ W2r,
                                               const float* __restrict__ W3l, const float* __restrict__ W3r,
                                               unsigned short* __restrict__ Wt1,
                                               unsigned short* __restrict__ Wt2,
                                               unsigned short* __restrict__ Wt3) {
    const int idx = blockIdx.x * 256 + threadIdx.x;
    if (idx < 16384) {                            // Wt1: 128 cols x 128 k
        const int c = idx >> 7, k = idx & 127;
        const float v = (c < 64) ? W1l[k * 64 + c] : W1r[k * 64 + (c - 64)];
        Wt1[c * 128 + k] = bf16rne(v);
    } else if (idx < 24576) {                     // Wt2: 128 cols x 64 k
        const int j = idx - 16384;
        const int c = j >> 6, k = j & 63;
        const float v = (c < 64) ? W2l[k * 64 + c] : W2r[k * 64 + (c - 64)];
        Wt2[c * 64 + k] = bf16rne(v);
    } else if (idx < 32768) {                     // Wt3: 128 cols x 64 k
        const int j = idx - 24576;
        const int c = j >> 6, k = j & 63;
        const float v = (c < 64) ? W3l[k * 64 + c] : W3r[k * 64 + (c - 64)];
        Wt3[c * 64 + k] = bf16rne(v);
    }
}

// ---------------- MFMA dual GEMM: [XL|XR] = X @ [Wl|Wr] + bias, bf16 in/out ----------------
// Block = 64 rows x 128 cols, full K in LDS. mfma_f32_16x16x32_bf16 fragments:
// A: row=lane&15, k=(lane>>4)*8+j; B: col=lane&15, k=(lane>>4)*8+j;
// D: col=lane&15, row=(lane>>4)*4+reg. Row pad +8 bf16 -> 2-way (free) LDS banks.
// W pre-converted bf16 col-major (k_wprep) -> staging is pure uint4 copies.

template <int K, bool F32IN>
__global__ __launch_bounds__(256) void k_gemm_mfma(const void* __restrict__ Xin,
                                                   const unsigned short* __restrict__ Wt,
                                                   const float* __restrict__ bl,
                                                   const float* __restrict__ br,
                                                   unsigned short* __restrict__ XLu,
                                                   unsigned short* __restrict__ XRu) {
    constexpr int KP = K + 8;
    __shared__ unsigned short sA[64 * KP];
    __shared__ unsigned short sB[128 * KP];
    const int t = threadIdx.x;
    const int w = t >> 6, lane = t & 63;
    const int r0 = blockIdx.x * 64;

    // stage B: pure vector copy of pre-converted weights
    {
        const uint4* Wu = (const uint4*)Wt;
#pragma unroll
        for (int idx = t; idx < 128 * (K / 8); idx += 256) {
            const int row = idx / (K / 8), q = idx % (K / 8);
            *(uint4*)&sB[row * KP + q * 8] = Wu[idx];
        }
    }
    // stage A: 64 rows x K
    if constexpr (F32IN) {
        const float* X = (const float*)Xin;
        for (int idx = t; idx < 64 * (K / 4); idx += 256) {
            const int row = idx / (K / 4), q = idx % (K / 4);
            const int rr = min(r0 + row, NNODES - 1);
            const float4 v = *(const float4*)&X[(size_t)rr * K + q * 4];
            unsigned* p = (unsigned*)&sA[row * KP + q * 4];
            p[0] = pack_bf2(v.x, v.y);
            p[1] = pack_bf2(v.z, v.w);
        }
    } else {
        const uint4* X = (const uint4*)Xin;      // packed bf16 rows: 8 x uint4
        for (int idx = t; idx < 64 * 8; idx += 256) {
            const int row = idx >> 3, q = idx & 7;
            const int rr = min(r0 + row, NNODES - 1);
            *(uint4*)&sA[row * KP + q * 8] = X[(size_t)rr * 8 + q];
        }
    }
    __syncthreads();

    f32x4 acc[8] = {};
    const int mrow = w * 16 + (lane & 15);
    const int kb = (lane >> 4) * 8;
#pragma unroll
    for (int kc = 0; kc < K / 32; ++kc) {
        const bf16x8 af = *(const bf16x8*)&sA[mrow * KP + kc * 32 + kb];
#pragma unroll
        for (int nt = 0; nt < 8; ++nt) {
            const bf16x8 bfr = *(const bf16x8*)&sB[(nt * 16 + (lane & 15)) * KP + kc * 32 + kb];
            acc[nt] = __builtin_amdgcn_mfma_f32_16x16x32_bf16(af, bfr, acc[nt], 0, 0, 0);
        }
    }

    // epilogue: bias + bf16 store
    const int colL = lane & 15;
    const int rbase = r0 + w * 16 + (lane >> 4) * 4;
#pragma unroll
    for (int nt = 0; nt < 8; ++nt) {
        const int col = nt * 16 + colL;
        const bool isL = col < 64;
        const float bv = isL ? bl[col] : br[col - 64];
        unsigned short* OUT = isL ? XLu : XRu;
        const int oc = isL ? col : col - 64;
#pragma unroll
        for (int r = 0; r < 4; ++r) {
            const int grow = rbase + r;
            if (grow < NNODES)
                OUT[(size_t)grow * 64 + oc] = bf16rne(acc[nt][r] + bv);
        }
    }
}

// ---------------- fused GATv2 edge pass ----------------
// One wave per node. lane = 8*group + fl; group g handles edge e+g (8/batch);
// lane holds features [fl*8, fl*8+8) from one uint4 of packed bf16.
// Fused leaky: att*leaky(m) = 0.6*(att.m) + 0.4*(att.|m|), |m| free modifier.
// Per-wave LDS combine, stride-65 scalar stores, no block barrier.
// Output H packed bf16 (32 uints/node). [R10 version — verified 73.5 us]

__global__ __launch_bounds__(256) void k_edge(const uint4* __restrict__ XLh,
                                              const uint4* __restrict__ XRh,
                                              const int* __restrict__ rowptr,
                                              const uint2* __restrict__ edata,
                                              const float* __restrict__ We,
                                              const float* __restrict__ att,
                                              const float* __restrict__ bias,
                                              const float* __restrict__ easum,
                                              unsigned* __restrict__ Hh) {
    __shared__ float red[4][8][65];              // bank = (g + 8*fl + k) % 32: 2/bank (free)
    const int wave = threadIdx.x >> 6, lane = threadIdx.x & 63;
    const int g = lane >> 3, fl = lane & 7;
    const int fo = fl * 8;
    float We8[8], att8[8];
    *(float4*)&We8[0] = *(const float4*)&We[fo];
    *(float4*)&We8[4] = *(const float4*)&We[fo + 4];
    *(float4*)&att8[0] = *(const float4*)&att[fo];
    *(float4*)&att8[4] = *(const float4*)&att[fo + 4];
    const float bias_l = bias[lane];
    const float ea_mean = easum[0] * (1.0f / NEDGES);

    const int i = blockIdx.x * 4 + wave;         // exact grid: always < NNODES

    float xr8[8], xl8[8], acc8[8];
    unpack_bf8(XRh[(size_t)i * 8 + fl], xr8);
    unpack_bf8(XLh[(size_t)i * 8 + fl], xl8);

    // self-loop (src=i, ea=ea_mean): wave-uniform logit
    {
        float s1 = 0.f, s2 = 0.f;
#pragma unroll
        for (int f = 0; f < 8; ++f) {
            const float m = fmaf(ea_mean, We8[f], xr8[f]) + xl8[f];
            s1 = fmaf(att8[f], m, s1);
            s2 = fmaf(att8[f], fabsf(m), s2);
        }
        float pt = fmaf(0.6f, s1, 0.4f * s2);
        pt += __shfl_xor(pt, 1);
        pt += __shfl_xor(pt, 2);
        pt += __shfl_xor(pt, 4);
        red[wave][0][64] = pt;                   // spare slot broadcast
    }
    float M = red[wave][0][64];
    __builtin_amdgcn_wave_barrier();
    float S = (g == 0) ? 1.f : 0.f;              // per-group partial denominator
#pragma unroll
    for (int f = 0; f < 8; ++f) acc8[f] = (g == 0) ? xl8[f] : 0.f;

    const int e0 = rowptr[i];
    const int ne = rowptr[i + 1] - e0;
    const uint2 z2 = make_uint2(0u, 0u);

    uint2 se = (g < ne) ? edata[e0 + g] : z2;    // meta prefetch, 1 batch ahead
    for (int e = 0; e < ne; e += 8) {
        const uint2 se_cur = se;
        const bool valid = (e + g) < ne;
        if (e + 8 + g < ne) se = edata[e0 + e + 8 + g];
        const int s = (int)(se_cur.x & 0x1FFFFu);
        const float eav = __uint_as_float(se_cur.y);
        float v8[8];
        unpack_bf8(XLh[(size_t)s * 8 + fl], v8);

        float s1 = 0.f, s2 = 0.f;
#pragma unroll
        for (int f = 0; f < 8; ++f) {
            const float m = fmaf(eav, We8[f], xr8[f]) + v8[f];
            s1 = fmaf(att8[f], m, s1);
            s2 = fmaf(att8[f], fabsf(m), s2);
        }
        float d = fmaf(0.6f, s1, 0.4f * s2);
        d += __shfl_xor(d, 1);
        d += __shfl_xor(d, 2);
        d += __shfl_xor(d, 4);                   // group-uniform logit
        const float a = valid ? d : -1e30f;

        if (__any(a > M)) {                      // ballot; wave-uniform branch
            float am = fmaxf(a, __shfl_xor(a, 8));
            am = fmaxf(am, __shfl_xor(am, 16));
            am = fmaxf(am, __shfl_xor(am, 32));
            const float sc = __expf(M - am);     // exact rescale
            S *= sc;
#pragma unroll
            for (int f = 0; f < 8; ++f) acc8[f] *= sc;
            M = am;
        }
        const float p = __expf(a - M);           // 0 for invalid groups
        S += p;                                  // group-partial (deferred reduce)
#pragma unroll
        for (int f = 0; f < 8; ++f) acc8[f] = fmaf(p, v8[f], acc8[f]);
    }

    // reduce S across groups (xor 8/16/32 touches g bits only)
    S += __shfl_xor(S, 8);
    S += __shfl_xor(S, 16);
    S += __shfl_xor(S, 32);

    // per-wave LDS transpose-combine (no inter-wave sharing -> no block barrier)
#pragma unroll
    for (int k = 0; k < 8; ++k) red[wave][g][fo + k] = acc8[k];
    asm volatile("" ::: "memory");
    __builtin_amdgcn_wave_barrier();             // DS ops complete in-order per wave
    float o = 0.f;
#pragma unroll
    for (int gg = 0; gg < 8; ++gg) o += red[wave][gg][lane];
    o = fmaxf(o / S + bias_l, 0.f);              // bias + fused ReLU
    const float on = __shfl_xor(o, 1);
    if (!(lane & 1))
        Hh[(size_t)i * 32 + (lane >> 1)] = pack_bf2(o, on);   // packed bf16 store
}

// ---------------- tail: mean pool + linear + softmax ----------------

__global__ __launch_bounds__(256) void k_colsum(const unsigned* __restrict__ Hh,
                                                float* __restrict__ gsum) {
    const int t = threadIdx.x;
    const int c = t & 31;                        // uint column = feature pair
    const int rl = t >> 5;                       // 0..7
    float s0 = 0.f, s1 = 0.f;
    for (int r = blockIdx.x * 8 + rl; r < NNODES; r += gridDim.x * 8) {
        const unsigned u = Hh[(size_t)r * 32 + c];
        s0 += __uint_as_float(u << 16);
        s1 += __uint_as_float(u & 0xFFFF0000u);
    }
    __shared__ float ls[8][64];
    ls[rl][2 * c] = s0;
    ls[rl][2 * c + 1] = s1;
    __syncthreads();
    if (t < 64) {
        float s = 0.f;
#pragma unroll
        for (int q = 0; q < 8; ++q) s += ls[q][t];
        atomicAdd(&gsum[t], s);
    }
}

__global__ __launch_bounds__(64) void k_head(const float* __restrict__ gsum,
                                             const float* __restrict__ Wlin,
                                             const float* __restrict__ blin,
                                             float* __restrict__ out) {
    int lane = threadIdx.x;
    float g = gsum[lane] * (1.0f / NNODES);
    float a0 = wave_sum64(g * Wlin[lane * 2 + 0]);
    float a1 = wave_sum64(g * Wlin[lane * 2 + 1]);
    if (lane == 0) {
        float l0 = a0 + blin[0], l1 = a1 + blin[1];
        float mx = fmaxf(l0, l1);
        float e0 = __expf(l0 - mx), e1 = __expf(l1 - mx);
        float inv = 1.f / (e0 + e1);
        out[0] = e0 * inv;
        out[1] = e1 * inv;
    }
}

extern "C" void kernel_launch(void* const* d_in, const int* in_sizes, int n_in,
                              void* d_out, int out_size, void* d_ws, size_t ws_size,
                              hipStream_t stream) {
    const float* x = (const float*)d_in[0];
    const int* ei = (const int*)d_in[1];
    const float* ea = (const float*)d_in[2];
    const int* src = ei;
    const int* dst = ei + NEDGES;
    auto W = [&](int i) { return (const float*)d_in[i]; };

    char* ws = (char*)d_ws;
    size_t off = 0;
    auto alloc = [&](size_t bytes) {
        void* p = ws + off;
        off += (bytes + 255) & ~(size_t)255;
        return p;
    };
    unsigned short* XLu = (unsigned short*)alloc((size_t)NNODES * 64 * 2);  // packed bf16
    unsigned short* XRu = (unsigned short*)alloc((size_t)NNODES * 64 * 2);  // packed bf16
    unsigned* Hh = (unsigned*)alloc((size_t)NBLK * CHUNK * 8);  // 12.82 MB: packed bf16 H, aliased by tmps
    int* rowptr = (int*)alloc((size_t)(NNODES + 1) * 4);
    uint2* edata = (uint2*)alloc((size_t)NEDGES * 8);
    float* easum = (float*)alloc(4);
    float* gsum = (float*)alloc(64 * 4);
    int* gcnt = (int*)alloc((size_t)FLATN * 4);
    int* lscan = (int*)alloc((size_t)FLATN * 4);
    int* goff = (int*)alloc((size_t)FLATN * 4);
    int* part2 = (int*)alloc((size_t)SCB * 4);
    int* boff2 = (int*)alloc((size_t)SCB * 4);
    unsigned short* Wt1 = (unsigned short*)alloc(16384 * 2);
    unsigned short* Wt2 = (unsigned short*)alloc(8192 * 2);
    unsigned short* Wt3 = (unsigned short*)alloc(8192 * 2);
    uint2* tmps = (uint2*)Hh;  // Hh dead until layer-1 k_edge; sort uses it first

    hipMemsetAsync(easum, 0, 4, stream);
    hipMemsetAsync(gsum, 0, 64 * 4, stream);

    k_wprep<<<128, 256, 0, stream>>>(W(3), W(5), W(10), W(12), W(17), W(19), Wt1, Wt2, Wt3);
    k_lsort<<<NBLK, 256, 0, stream>>>(src, dst, ea, tmps, gcnt, lscan, easum);
    k_part2<<<SCB, 256, 0, stream>>>(gcnt, FLATN, part2);
    k_scanb2<<<1, 1024, 0, stream>>>(part2, SCB, boff2, rowptr);
    k_scanfin2<<<SCB, 256, 0, stream>>>(gcnt, FLATN, boff2, goff);
    k_fsort<<<NB, 256, 0, stream>>>(tmps, lscan, goff, rowptr, edata);

    int gemm_grid = (NNODES + 63) / 64;   // 1563
    int edge_grid = NNODES / 4;           // exact: one wave per node

    k_gemm_mfma<128, true><<<gemm_grid, 256, 0, stream>>>(x, Wt1, W(4), W(6), XLu, XRu);
    k_edge<<<edge_grid, 256, 0, stream>>>((const uint4*)XLu, (const uint4*)XRu, rowptr, edata,
                                          W(7), W(8), W(9), easum, Hh);
    k_gemm_mfma<64, false><<<gemm_grid, 256, 0, stream>>>(Hh, Wt2, W(11), W(13), XLu, XRu);
    k_edge<<<edge_grid, 256, 0, stream>>>((const uint4*)XLu, (const uint4*)XRu, rowptr, edata,
                                          W(14), W(15), W(16), easum, Hh);
    k_gemm_mfma<64, false><<<gemm_grid, 256, 0, stream>>>(Hh, Wt3, W(18), W(20), XLu, XRu);
    k_edge<<<edge_grid, 256, 0, stream>>>((const uint4*)XLu, (const uint4*)XRu, rowptr, edata,
                                          W(21), W(22), W(23), easum, Hh);

    k_colsum<<<256, 256, 0, stream>>>(Hh, gsum);
    k_head<<<1, 64, 0, stream>>>(gsum, W(24), W(25), (float*)d_out);
}

// Round 14
// 306.715 us; speedup vs baseline: 1.2443x; 1.1303x over previous
//
#include <hip/hip_runtime.h>
#include <hip/hip_bf16.h>

#define NNODES 100000
#define NEDGES 1600000
#define NEG_SLOPE 0.2f

#define CHUNK 4096
#define EPT 16                                  // edges per thread in k_lsort
#define NBLK ((NEDGES + CHUNK - 1) / CHUNK)     // 391 sort blocks
#define NB ((NNODES + 255) / 256)               // 391 buckets (256 nodes each)
#define FLATN (NB * NBLK)                       // 152881
#define SCB ((FLATN + 255) / 256)               // 598
#define FCAP 5632                               // bucket entry cap (mean 4092, +24 sigma)

typedef __attribute__((ext_vector_type(8))) short bf16x8;
typedef __attribute__((ext_vector_type(4))) float f32x4;

__device__ __forceinline__ float wave_sum64(float v) {
#pragma unroll
    for (int off = 1; off < 64; off <<= 1) v += __shfl_xor(v, off, 64);
    return v;
}

__device__ __forceinline__ int wave_sum64i(int v) {
#pragma unroll
    for (int off = 1; off < 64; off <<= 1) v += __shfl_xor(v, off, 64);
    return v;
}

// f32 -> bf16 (RNE)
__device__ __forceinline__ unsigned short bf16rne(float a) {
    unsigned u = __float_as_uint(a);
    return (unsigned short)((u + 0x7FFFu + ((u >> 16) & 1u)) >> 16);
}

// pack two f32 -> one uint of 2 bf16 (RNE); low ushort = a
__device__ __forceinline__ unsigned pack_bf2(float a, float b) {
    unsigned ua = __float_as_uint(a), ub = __float_as_uint(b);
    ua = (ua + 0x7FFFu + ((ua >> 16) & 1u)) >> 16;
    ub = (ub + 0x7FFFu + ((ub >> 16) & 1u));
    return ua | (ub & 0xFFFF0000u);
}

__device__ __forceinline__ void unpack_bf8(uint4 w, float* f) {
    f[0] = __uint_as_float(w.x << 16);
    f[1] = __uint_as_float(w.x & 0xFFFF0000u);
    f[2] = __uint_as_float(w.y << 16);
    f[3] = __uint_as_float(w.y & 0xFFFF0000u);
    f[4] = __uint_as_float(w.z << 16);
    f[5] = __uint_as_float(w.z & 0xFFFF0000u);
    f[6] = __uint_as_float(w.w << 16);
    f[7] = __uint_as_float(w.w & 0xFFFF0000u);
}

// ---------------- phase A: per-chunk counting sort by bucket (all-coalesced) ----------------

__global__ __launch_bounds__(256) void k_lsort(const int* __restrict__ src,
                                               const int* __restrict__ dst,
                                               const float* __restrict__ ea,
                                               uint2* __restrict__ tmps,
                                               int* __restrict__ gcnt,
                                               int* __restrict__ lscan,
                                               float* __restrict__ easum) {
    __shared__ uint2 ent[CHUNK];                 // 32 KB
    __shared__ unsigned short perm[CHUNK];       // 8 KB
    __shared__ int hist[NB];
    __shared__ int cur[NB];
    __shared__ float ws[4];
    const int t = threadIdx.x;
    const int j = blockIdx.x;
    const int base = j * CHUNK;
    const int n = min(CHUNK, NEDGES - base);

    for (int b = t; b < NB; b += 256) hist[b] = 0;
    __syncthreads();

    int bkt[EPT];
    float s = 0.f;
#pragma unroll
    for (int k = 0; k < EPT; ++k) {
        const int l = t + k * 256;
        bkt[k] = -1;
        if (l < n) {
            const int i = base + l;
            const int d = dst[i];
            const float e = ea[i];
            const int b = d >> 8;
            bkt[k] = b;
            ent[l] = make_uint2((unsigned)src[i] | ((unsigned)(d & 255) << 17),
                                __float_as_uint(e));
            atomicAdd(&hist[b], 1);
            s += e;
        }
    }
    s = wave_sum64(s);
    if ((t & 63) == 0) ws[t >> 6] = s;
    __syncthreads();
    if (t == 0) atomicAdd(easum, ws[0] + ws[1] + ws[2] + ws[3]);

    // exclusive scan of hist[0..NB) -> cur, wave 0 only (56 lanes x 7 elems)
    if (t < 64) {
        int x[7];
        int run = 0;
#pragma unroll
        for (int q = 0; q < 7; ++q) {
            const int idx = t * 7 + q;
            x[q] = (idx < NB) ? hist[idx] : 0;
            run += x[q];
        }
        int inc = run;
#pragma unroll
        for (int o = 1; o < 64; o <<= 1) {
            int u = __shfl_up(inc, o, 64);
            if (t >= o) inc += u;
        }
        int r = inc - run;   // lane-exclusive
#pragma unroll
        for (int q = 0; q < 7; ++q) {
            const int idx = t * 7 + q;
            if (idx < NB) cur[idx] = r;
            r += x[q];
        }
    }
    __syncthreads();

#pragma unroll
    for (int k = 0; k < EPT; ++k) {
        if (bkt[k] >= 0) {
            const int r = atomicAdd(&cur[bkt[k]], 1);
            perm[r] = (unsigned short)(t + k * 256);
        }
    }
    __syncthreads();

    for (int o = t; o < n; o += 256)
        tmps[base + o] = ent[perm[o]];           // coalesced global write
    for (int b = t; b < NB; b += 256) {
        gcnt[b * NBLK + j] = hist[b];            // bucket-major (for flat scan)
        lscan[j * NB + b] = cur[b] - hist[b];    // local exclusive offset
    }
}

// ---------------- flat exclusive scan of gcnt[FLATN] -> goff ----------------

__global__ __launch_bounds__(256) void k_part2(const int* __restrict__ v, int n,
                                               int* __restrict__ bsum) {
    int i = blockIdx.x * 256 + threadIdx.x;
    int x = (i < n) ? v[i] : 0;
    x = wave_sum64i(x);
    __shared__ int wsh[4];
    if ((threadIdx.x & 63) == 0) wsh[threadIdx.x >> 6] = x;
    __syncthreads();
    if (threadIdx.x == 0) bsum[blockIdx.x] = wsh[0] + wsh[1] + wsh[2] + wsh[3];
}

__global__ __launch_bounds__(1024) void k_scanb2(const int* __restrict__ bsum, int nb,
                                                 int* __restrict__ boff,
                                                 int* __restrict__ rowptr) {
    __shared__ int sh[1024];
    int t = threadIdx.x;
    int v = (t < nb) ? bsum[t] : 0;
    sh[t] = v;
    __syncthreads();
    for (int off = 1; off < 1024; off <<= 1) {
        int u = (t >= off) ? sh[t - off] : 0;
        __syncthreads();
        sh[t] += u;
        __syncthreads();
    }
    if (t < nb) boff[t] = sh[t] - v;
    if (t == 0) rowptr[NNODES] = NEDGES;
}

__global__ __launch_bounds__(256) void k_scanfin2(const int* __restrict__ v, int n,
                                                  const int* __restrict__ boff,
                                                  int* __restrict__ out) {
    int t = threadIdx.x, lane = t & 63, wave = t >> 6;
    int i = blockIdx.x * 256 + t;
    int x = (i < n) ? v[i] : 0;
    int orig = x;
#pragma unroll
    for (int off = 1; off < 64; off <<= 1) {
        int u = __shfl_up(x, off, 64);
        if (lane >= off) x += u;
    }
    __shared__ int wsh[4];
    if (lane == 63) wsh[wave] = x;
    __syncthreads();
    int wexc = 0;
    for (int w = 0; w < wave; ++w) wexc += wsh[w];
    if (i < n) out[i] = boff[blockIdx.x] + wexc + x - orig;
}

// ---------------- phase C: per-bucket gather + LDS counting sort by node ----------------

__global__ __launch_bounds__(256) void k_fsort(const uint2* __restrict__ tmps,
                                               const int* __restrict__ lscan,
                                               const int* __restrict__ goff,
                                               int* __restrict__ rowptr,
                                               uint2* __restrict__ edata) {
    __shared__ uint2 ent[FCAP];                  // 44 KB
    __shared__ unsigned short perm[FCAP];        // 11 KB
    __shared__ int joff[NBLK + 1];
    __shared__ int jsrc[NBLK];
    __shared__ int hist[256];
    __shared__ int cur[256];
    const int b = blockIdx.x;
    const int t = threadIdx.x;
    const int base = goff[b * NBLK];             // bucket base position in edata

    for (int q = t; q < 256; q += 256) hist[q] = 0;
    for (int j = t; j < NBLK; j += 256) {
        joff[j] = goff[b * NBLK + j] - base;
        jsrc[j] = j * CHUNK + lscan[j * NB + b];
    }
    if (t == 0) joff[NBLK] = ((b == NB - 1) ? NEDGES : goff[(b + 1) * NBLK]) - base;
    __syncthreads();
    const int T = min(joff[NBLK], FCAP);

    for (int idx = t; idx < T; idx += 256) {
        int lo = 0, hi = NBLK;
        while (hi - lo > 1) { int mid = (lo + hi) >> 1; if (joff[mid] <= idx) lo = mid; else hi = mid; }
        const uint2 e = tmps[jsrc[lo] + (idx - joff[lo])];   // piecewise-coalesced
        ent[idx] = e;
        atomicAdd(&hist[(e.x >> 17) & 255u], 1);
    }
    __syncthreads();

    // exclusive scan hist[0..256) -> cur, wave 0 (64 lanes x 4)
    if (t < 64) {
        int x[4];
        int run = 0;
#pragma unroll
        for (int q = 0; q < 4; ++q) { x[q] = hist[t * 4 + q]; run += x[q]; }
        int inc = run;
#pragma unroll
        for (int o = 1; o < 64; o <<= 1) {
            int u = __shfl_up(inc, o, 64);
            if (t >= o) inc += u;
        }
        int r = inc - run;
#pragma unroll
        for (int q = 0; q < 4; ++q) { cur[t * 4 + q] = r; r += x[q]; }
    }
    __syncthreads();

    {
        const int i = b * 256 + t;
        if (i < NNODES) rowptr[i] = base + cur[t];
    }
    __syncthreads();    // rowptr reads of cur must complete before rank mutation

    for (int idx = t; idx < T; idx += 256) {
        const int d = (int)((ent[idx].x >> 17) & 255u);
        const int r = atomicAdd(&cur[d], 1);
        perm[r] = (unsigned short)idx;
    }
    __syncthreads();
    for (int k = t; k < T; k += 256)
        edata[base + k] = ent[perm[k]];          // coalesced global write
}

// ---------------- weight pre-conversion: f32 [K][64] x2 -> bf16 col-major [128][K] ----------------

__global__ __launch_bounds__(256) void k_wprep(const float* __restrict__ W1l, const float* __restrict__ W1r,
                                               const float* __restrict__ W2l, const float* __restrict__ W2r,
                                               const float* __restrict__ W3l, const float* __restrict__ W3r,
                                               unsigned short* __restrict__ Wt1,
                                               unsigned short* __restrict__ Wt2,
                                               unsigned short* __restrict__ Wt3) {
    const int idx = blockIdx.x * 256 + threadIdx.x;
    if (idx < 16384) {                            // Wt1: 128 cols x 128 k
        const int c = idx >> 7, k = idx & 127;
        const float v = (c < 64) ? W1l[k * 64 + c] : W1r[k * 64 + (c - 64)];
        Wt1[c * 128 + k] = bf16rne(v);
    } else if (idx < 24576) {                     // Wt2: 128 cols x 64 k
        const int j = idx - 16384;
        const int c = j >> 6, k = j & 63;
        const float v = (c < 64) ? W2l[k * 64 + c] : W2r[k * 64 + (c - 64)];
        Wt2[c * 64 + k] = bf16rne(v);
    } else if (idx < 32768) {                     // Wt3: 128 cols x 64 k
        const int j = idx - 24576;
        const int c = j >> 6, k = j & 63;
        const float v = (c < 64) ? W3l[k * 64 + c] : W3r[k * 64 + (c - 64)];
        Wt3[c * 64 + k] = bf16rne(v);
    }
}

// ---------------- MFMA dual GEMM: [XL|XR] = X @ [Wl|Wr] + bias, bf16 in/out ----------------
// Block = 64 rows x 128 cols, full K in LDS. mfma_f32_16x16x32_bf16 fragments:
// A: row=lane&15, k=(lane>>4)*8+j; B: col=lane&15, k=(lane>>4)*8+j;
// D: col=lane&15, row=(lane>>4)*4+reg. Row pad +8 bf16 -> 2-way (free) LDS banks.
// W pre-converted bf16 col-major (k_wprep) -> staging is pure uint4 copies.

template <int K, bool F32IN>
__global__ __launch_bounds__(256) void k_gemm_mfma(const void* __restrict__ Xin,
                                                   const unsigned short* __restrict__ Wt,
                                                   const float* __restrict__ bl,
                                                   const float* __restrict__ br,
                                                   unsigned short* __restrict__ XLu,
                                                   unsigned short* __restrict__ XRu) {
    constexpr int KP = K + 8;
    __shared__ unsigned short sA[64 * KP];
    __shared__ unsigned short sB[128 * KP];
    const int t = threadIdx.x;
    const int w = t >> 6, lane = t & 63;
    const int r0 = blockIdx.x * 64;

    // stage B: pure vector copy of pre-converted weights
    {
        const uint4* Wu = (const uint4*)Wt;
#pragma unroll
        for (int idx = t; idx < 128 * (K / 8); idx += 256) {
            const int row = idx / (K / 8), q = idx % (K / 8);
            *(uint4*)&sB[row * KP + q * 8] = Wu[idx];
        }
    }
    // stage A: 64 rows x K
    if constexpr (F32IN) {
        const float* X = (const float*)Xin;
        for (int idx = t; idx < 64 * (K / 4); idx += 256) {
            const int row = idx / (K / 4), q = idx % (K / 4);
            const int rr = min(r0 + row, NNODES - 1);
            const float4 v = *(const float4*)&X[(size_t)rr * K + q * 4];
            unsigned* p = (unsigned*)&sA[row * KP + q * 4];
            p[0] = pack_bf2(v.x, v.y);
            p[1] = pack_bf2(v.z, v.w);
        }
    } else {
        const uint4* X = (const uint4*)Xin;      // packed bf16 rows: 8 x uint4
        for (int idx = t; idx < 64 * 8; idx += 256) {
            const int row = idx >> 3, q = idx & 7;
            const int rr = min(r0 + row, NNODES - 1);
            *(uint4*)&sA[row * KP + q * 8] = X[(size_t)rr * 8 + q];
        }
    }
    __syncthreads();

    f32x4 acc[8] = {};
    const int mrow = w * 16 + (lane & 15);
    const int kb = (lane >> 4) * 8;
#pragma unroll
    for (int kc = 0; kc < K / 32; ++kc) {
        const bf16x8 af = *(const bf16x8*)&sA[mrow * KP + kc * 32 + kb];
#pragma unroll
        for (int nt = 0; nt < 8; ++nt) {
            const bf16x8 bfr = *(const bf16x8*)&sB[(nt * 16 + (lane & 15)) * KP + kc * 32 + kb];
            acc[nt] = __builtin_amdgcn_mfma_f32_16x16x32_bf16(af, bfr, acc[nt], 0, 0, 0);
        }
    }

    // epilogue: bias + bf16 store
    const int colL = lane & 15;
    const int rbase = r0 + w * 16 + (lane >> 4) * 4;
#pragma unroll
    for (int nt = 0; nt < 8; ++nt) {
        const int col = nt * 16 + colL;
        const bool isL = col < 64;
        const float bv = isL ? bl[col] : br[col - 64];
        unsigned short* OUT = isL ? XLu : XRu;
        const int oc = isL ? col : col - 64;
#pragma unroll
        for (int r = 0; r < 4; ++r) {
            const int grow = rbase + r;
            if (grow < NNODES)
                OUT[(size_t)grow * 64 + oc] = bf16rne(acc[nt][r] + bv);
        }
    }
}

// ---------------- fused GATv2 edge pass ----------------
// One wave per node. lane = 8*group + fl; group g handles edge e+g (8/batch);
// lane holds features [fl*8, fl*8+8) from one uint4 of packed bf16.
// Fixed-base softmax: C = self-loop logit (softmax is shift-invariant; any
// constant works, p = exp(a - C) stays within f32 range for these magnitudes).
// Removes ballot + cross-group max + rescale from the loop entirely.
// Fused leaky: att*leaky(m) = 0.6*(att.m) + 0.4*(att.|m|), |m| free modifier.
// Per-wave LDS combine, stride-65 scalar stores, no block barrier.

__global__ __launch_bounds__(256) void k_edge(const uint4* __restrict__ XLh,
                                              const uint4* __restrict__ XRh,
                                              const int* __restrict__ rowptr,
                                              const uint2* __restrict__ edata,
                                              const float* __restrict__ We,
                                              const float* __restrict__ att,
                                              const float* __restrict__ bias,
                                              const float* __restrict__ easum,
                                              unsigned* __restrict__ Hh) {
    __shared__ float red[4][8][65];              // bank = (g + 8*fl + k) % 32: 2/bank (free)
    const int wave = threadIdx.x >> 6, lane = threadIdx.x & 63;
    const int g = lane >> 3, fl = lane & 7;
    const int fo = fl * 8;
    float We8[8], att8[8];
    *(float4*)&We8[0] = *(const float4*)&We[fo];
    *(float4*)&We8[4] = *(const float4*)&We[fo + 4];
    *(float4*)&att8[0] = *(const float4*)&att[fo];
    *(float4*)&att8[4] = *(const float4*)&att[fo + 4];
    const float bias_l = bias[lane];
    const float ea_mean = easum[0] * (1.0f / NEDGES);

    const int i = blockIdx.x * 4 + wave;         // exact grid: always < NNODES

    float xr8[8], xl8[8], acc8[8];
    unpack_bf8(XRh[(size_t)i * 8 + fl], xr8);
    unpack_bf8(XLh[(size_t)i * 8 + fl], xl8);

    // self-loop logit (src=i, ea=ea_mean): groups compute identical values ->
    // after the intra-group xor reduce, M is already wave-uniform.
    float M;
    {
        float s1 = 0.f, s2 = 0.f;
#pragma unroll
        for (int f = 0; f < 8; ++f) {
            const float m = fmaf(ea_mean, We8[f], xr8[f]) + xl8[f];
            s1 = fmaf(att8[f], m, s1);
            s2 = fmaf(att8[f], fabsf(m), s2);
        }
        float pt = fmaf(0.6f, s1, 0.4f * s2);
        pt += __shfl_xor(pt, 1);
        pt += __shfl_xor(pt, 2);
        pt += __shfl_xor(pt, 4);
        M = pt;                                  // fixed softmax base
    }
    float S = (g == 0) ? 1.f : 0.f;              // self-loop: exp(M-M)=1, group 0 only
#pragma unroll
    for (int f = 0; f < 8; ++f) acc8[f] = (g == 0) ? xl8[f] : 0.f;

    const int e0 = rowptr[i];
    const int ne = rowptr[i + 1] - e0;
    const uint2 z2 = make_uint2(0u, 0u);

    uint2 se = (g < ne) ? edata[e0 + g] : z2;    // meta prefetch, 1 batch ahead
    for (int e = 0; e < ne; e += 8) {
        const uint2 se_cur = se;
        const bool valid = (e + g) < ne;
        if (e + 8 + g < ne) se = edata[e0 + e + 8 + g];
        const int s = (int)(se_cur.x & 0x1FFFFu);
        const float eav = __uint_as_float(se_cur.y);
        float v8[8];
        unpack_bf8(XLh[(size_t)s * 8 + fl], v8);

        float s1 = 0.f, s2 = 0.f;
#pragma unroll
        for (int f = 0; f < 8; ++f) {
            const float m = fmaf(eav, We8[f], xr8[f]) + v8[f];
            s1 = fmaf(att8[f], m, s1);
            s2 = fmaf(att8[f], fabsf(m), s2);
        }
        float d = fmaf(0.6f, s1, 0.4f * s2);
        d += __shfl_xor(d, 1);
        d += __shfl_xor(d, 2);
        d += __shfl_xor(d, 4);                   // group-uniform logit
        const float a = valid ? d : -1e30f;      // exp(-inf) = 0 for pad groups

        const float p = __expf(a - M);           // fixed base: no max tracking
        S += p;                                  // group-partial (deferred reduce)
#pragma unroll
        for (int f = 0; f < 8; ++f) acc8[f] = fmaf(p, v8[f], acc8[f]);
    }

    // reduce S across groups (xor 8/16/32 touches g bits only)
    S += __shfl_xor(S, 8);
    S += __shfl_xor(S, 16);
    S += __shfl_xor(S, 32);

    // per-wave LDS transpose-combine (no inter-wave sharing -> no block barrier)
#pragma unroll
    for (int k = 0; k < 8; ++k) red[wave][g][fo + k] = acc8[k];
    asm volatile("" ::: "memory");
    __builtin_amdgcn_wave_barrier();             // DS ops complete in-order per wave
    float o = 0.f;
#pragma unroll
    for (int gg = 0; gg < 8; ++gg) o += red[wave][gg][lane];
    o = fmaxf(o / S + bias_l, 0.f);              // bias + fused ReLU
    const float on = __shfl_xor(o, 1);
    if (!(lane & 1))
        Hh[(size_t)i * 32 + (lane >> 1)] = pack_bf2(o, on);   // packed bf16 store
}

// ---------------- tail: mean pool + linear + softmax ----------------

__global__ __launch_bounds__(256) void k_colsum(const unsigned* __restrict__ Hh,
                                                float* __restrict__ gsum) {
    const int t = threadIdx.x;
    const int c = t & 31;                        // uint column = feature pair
    const int rl = t >> 5;                       // 0..7
    float s0 = 0.f, s1 = 0.f;
    for (int r = blockIdx.x * 8 + rl; r < NNODES; r += gridDim.x * 8) {
        const unsigned u = Hh[(size_t)r * 32 + c];
        s0 += __uint_as_float(u << 16);
        s1 += __uint_as_float(u & 0xFFFF0000u);
    }
    __shared__ float ls[8][64];
    ls[rl][2 * c] = s0;
    ls[rl][2 * c + 1] = s1;
    __syncthreads();
    if (t < 64) {
        float s = 0.f;
#pragma unroll
        for (int q = 0; q < 8; ++q) s += ls[q][t];
        atomicAdd(&gsum[t], s);
    }
}

__global__ __launch_bounds__(64) void k_head(const float* __restrict__ gsum,
                                             const float* __restrict__ Wlin,
                                             const float* __restrict__ blin,
                                             float* __restrict__ out) {
    int lane = threadIdx.x;
    float g = gsum[lane] * (1.0f / NNODES);
    float a0 = wave_sum64(g * Wlin[lane * 2 + 0]);
    float a1 = wave_sum64(g * Wlin[lane * 2 + 1]);
    if (lane == 0) {
        float l0 = a0 + blin[0], l1 = a1 + blin[1];
        float mx = fmaxf(l0, l1);
        float e0 = __expf(l0 - mx), e1 = __expf(l1 - mx);
        float inv = 1.f / (e0 + e1);
        out[0] = e0 * inv;
        out[1] = e1 * inv;
    }
}

extern "C" void kernel_launch(void* const* d_in, const int* in_sizes, int n_in,
                              void* d_out, int out_size, void* d_ws, size_t ws_size,
                              hipStream_t stream) {
    const float* x = (const float*)d_in[0];
    const int* ei = (const int*)d_in[1];
    const float* ea = (const float*)d_in[2];
    const int* src = ei;
    const int* dst = ei + NEDGES;
    auto W = [&](int i) { return (const float*)d_in[i]; };

    char* ws = (char*)d_ws;
    size_t off = 0;
    auto alloc = [&](size_t bytes) {
        void* p = ws + off;
        off += (bytes + 255) & ~(size_t)255;
        return p;
    };
    unsigned short* XLu = (unsigned short*)alloc((size_t)NNODES * 64 * 2);  // packed bf16
    unsigned short* XRu = (unsigned short*)alloc((size_t)NNODES * 64 * 2);  // packed bf16
    unsigned* Hh = (unsigned*)alloc((size_t)NBLK * CHUNK * 8);  // 12.82 MB: packed bf16 H, aliased by tmps
    int* rowptr = (int*)alloc((size_t)(NNODES + 1) * 4);
    uint2* edata = (uint2*)alloc((size_t)NEDGES * 8);
    float* easum = (float*)alloc(4);
    float* gsum = (float*)alloc(64 * 4);
    int* gcnt = (int*)alloc((size_t)FLATN * 4);
    int* lscan = (int*)alloc((size_t)FLATN * 4);
    int* goff = (int*)alloc((size_t)FLATN * 4);
    int* part2 = (int*)alloc((size_t)SCB * 4);
    int* boff2 = (int*)alloc((size_t)SCB * 4);
    unsigned short* Wt1 = (unsigned short*)alloc(16384 * 2);
    unsigned short* Wt2 = (unsigned short*)alloc(8192 * 2);
    unsigned short* Wt3 = (unsigned short*)alloc(8192 * 2);
    uint2* tmps = (uint2*)Hh;  // Hh dead until layer-1 k_edge; sort uses it first

    hipMemsetAsync(easum, 0, 4, stream);
    hipMemsetAsync(gsum, 0, 64 * 4, stream);

    k_wprep<<<128, 256, 0, stream>>>(W(3), W(5), W(10), W(12), W(17), W(19), Wt1, Wt2, Wt3);
    k_lsort<<<NBLK, 256, 0, stream>>>(src, dst, ea, tmps, gcnt, lscan, easum);
    k_part2<<<SCB, 256, 0, stream>>>(gcnt, FLATN, part2);
    k_scanb2<<<1, 1024, 0, stream>>>(part2, SCB, boff2, rowptr);
    k_scanfin2<<<SCB, 256, 0, stream>>>(gcnt, FLATN, boff2, goff);
    k_fsort<<<NB, 256, 0, stream>>>(tmps, lscan, goff, rowptr, edata);

    int gemm_grid = (NNODES + 63) / 64;   // 1563
    int edge_grid = NNODES / 4;           // exact: one wave per node

    k_gemm_mfma<128, true><<<gemm_grid, 256, 0, stream>>>(x, Wt1, W(4), W(6), XLu, XRu);
    k_edge<<<edge_grid, 256, 0, stream>>>((const uint4*)XLu, (const uint4*)XRu, rowptr, edata,
                                          W(7), W(8), W(9), easum, Hh);
    k_gemm_mfma<64, false><<<gemm_grid, 256, 0, stream>>>(Hh, Wt2, W(11), W(13), XLu, XRu);
    k_edge<<<edge_grid, 256, 0, stream>>>((const uint4*)XLu, (const uint4*)XRu, rowptr, edata,
                                          W(14), W(15), W(16), easum, Hh);
    k_gemm_mfma<64, false><<<gemm_grid, 256, 0, stream>>>(Hh, Wt3, W(18), W(20), XLu, XRu);
    k_edge<<<edge_grid, 256, 0, stream>>>((const uint4*)XLu, (const uint4*)XRu, rowptr, edata,
                                          W(21), W(22), W(23), easum, Hh);

    k_colsum<<<256, 256, 0, stream>>>(Hh, gsum);
    k_head<<<1, 64, 0, stream>>>(gsum, W(24), W(25), (float*)d_out);
}

// Round 15
// 297.033 us; speedup vs baseline: 1.2848x; 1.0326x over previous
//
#include <hip/hip_runtime.h>
#include <hip/hip_bf16.h>

#define NNODES 100000
#define NEDGES 1600000
#define NEG_SLOPE 0.2f

#define CHUNK 4096
#define EPT 16                                  // edges per thread in k_lsort
#define NBLK ((NEDGES + CHUNK - 1) / CHUNK)     // 391 sort blocks
#define NB ((NNODES + 255) / 256)               // 391 buckets (256 nodes each)
#define FLATN (NB * NBLK)                       // 152881
#define SCB ((FLATN + 255) / 256)               // 598
#define FCAP 5632                               // bucket entry cap (mean 4092, +24 sigma)

typedef __attribute__((ext_vector_type(8))) _Float16 f16x8;
typedef __attribute__((ext_vector_type(2))) _Float16 h2;
typedef __attribute__((ext_vector_type(4))) float f32x4;

__device__ __forceinline__ float wave_sum64(float v) {
#pragma unroll
    for (int off = 1; off < 64; off <<= 1) v += __shfl_xor(v, off, 64);
    return v;
}

__device__ __forceinline__ int wave_sum64i(int v) {
#pragma unroll
    for (int off = 1; off < 64; off <<= 1) v += __shfl_xor(v, off, 64);
    return v;
}

// f32 -> f16 bits (RNE per IEEE conversion semantics)
__device__ __forceinline__ unsigned short f16rne(float a) {
    _Float16 h = (_Float16)a;
    unsigned short u;
    __builtin_memcpy(&u, &h, 2);
    return u;
}

// pack two f32 -> one uint of 2 f16
__device__ __forceinline__ unsigned packh2(float a, float b) {
    h2 v = {(_Float16)a, (_Float16)b};
    unsigned u;
    __builtin_memcpy(&u, &v, 4);
    return u;
}

__device__ __forceinline__ h2 habs(h2 x) {
    unsigned u;
    __builtin_memcpy(&u, &x, 4);
    u &= 0x7FFF7FFFu;
    h2 r;
    __builtin_memcpy(&r, &u, 4);
    return r;
}

// ---------------- phase A: per-chunk counting sort by bucket (all-coalesced) ----------------

__global__ __launch_bounds__(256) void k_lsort(const int* __restrict__ src,
                                               const int* __restrict__ dst,
                                               const float* __restrict__ ea,
                                               uint2* __restrict__ tmps,
                                               int* __restrict__ gcnt,
                                               int* __restrict__ lscan,
                                               float* __restrict__ easum) {
    __shared__ uint2 ent[CHUNK];                 // 32 KB
    __shared__ unsigned short perm[CHUNK];       // 8 KB
    __shared__ int hist[NB];
    __shared__ int cur[NB];
    __shared__ float ws[4];
    const int t = threadIdx.x;
    const int j = blockIdx.x;
    const int base = j * CHUNK;
    const int n = min(CHUNK, NEDGES - base);

    for (int b = t; b < NB; b += 256) hist[b] = 0;
    __syncthreads();

    int bkt[EPT];
    float s = 0.f;
#pragma unroll
    for (int k = 0; k < EPT; ++k) {
        const int l = t + k * 256;
        bkt[k] = -1;
        if (l < n) {
            const int i = base + l;
            const int d = dst[i];
            const float e = ea[i];
            const int b = d >> 8;
            bkt[k] = b;
            ent[l] = make_uint2((unsigned)src[i] | ((unsigned)(d & 255) << 17),
                                __float_as_uint(e));
            atomicAdd(&hist[b], 1);
            s += e;
        }
    }
    s = wave_sum64(s);
    if ((t & 63) == 0) ws[t >> 6] = s;
    __syncthreads();
    if (t == 0) atomicAdd(easum, ws[0] + ws[1] + ws[2] + ws[3]);

    // exclusive scan of hist[0..NB) -> cur, wave 0 only (56 lanes x 7 elems)
    if (t < 64) {
        int x[7];
        int run = 0;
#pragma unroll
        for (int q = 0; q < 7; ++q) {
            const int idx = t * 7 + q;
            x[q] = (idx < NB) ? hist[idx] : 0;
            run += x[q];
        }
        int inc = run;
#pragma unroll
        for (int o = 1; o < 64; o <<= 1) {
            int u = __shfl_up(inc, o, 64);
            if (t >= o) inc += u;
        }
        int r = inc - run;   // lane-exclusive
#pragma unroll
        for (int q = 0; q < 7; ++q) {
            const int idx = t * 7 + q;
            if (idx < NB) cur[idx] = r;
            r += x[q];
        }
    }
    __syncthreads();

#pragma unroll
    for (int k = 0; k < EPT; ++k) {
        if (bkt[k] >= 0) {
            const int r = atomicAdd(&cur[bkt[k]], 1);
            perm[r] = (unsigned short)(t + k * 256);
        }
    }
    __syncthreads();

    for (int o = t; o < n; o += 256)
        tmps[base + o] = ent[perm[o]];           // coalesced global write
    for (int b = t; b < NB; b += 256) {
        gcnt[b * NBLK + j] = hist[b];            // bucket-major (for flat scan)
        lscan[j * NB + b] = cur[b] - hist[b];    // local exclusive offset
    }
}

// ---------------- flat exclusive scan of gcnt[FLATN] -> goff ----------------

__global__ __launch_bounds__(256) void k_part2(const int* __restrict__ v, int n,
                                               int* __restrict__ bsum) {
    int i = blockIdx.x * 256 + threadIdx.x;
    int x = (i < n) ? v[i] : 0;
    x = wave_sum64i(x);
    __shared__ int wsh[4];
    if ((threadIdx.x & 63) == 0) wsh[threadIdx.x >> 6] = x;
    __syncthreads();
    if (threadIdx.x == 0) bsum[blockIdx.x] = wsh[0] + wsh[1] + wsh[2] + wsh[3];
}

__global__ __launch_bounds__(1024) void k_scanb2(const int* __restrict__ bsum, int nb,
                                                 int* __restrict__ boff,
                                                 int* __restrict__ rowptr) {
    __shared__ int sh[1024];
    int t = threadIdx.x;
    int v = (t < nb) ? bsum[t] : 0;
    sh[t] = v;
    __syncthreads();
    for (int off = 1; off < 1024; off <<= 1) {
        int u = (t >= off) ? sh[t - off] : 0;
        __syncthreads();
        sh[t] += u;
        __syncthreads();
    }
    if (t < nb) boff[t] = sh[t] - v;
    if (t == 0) rowptr[NNODES] = NEDGES;
}

__global__ __launch_bounds__(256) void k_scanfin2(const int* __restrict__ v, int n,
                                                  const int* __restrict__ boff,
                                                  int* __restrict__ out) {
    int t = threadIdx.x, lane = t & 63, wave = t >> 6;
    int i = blockIdx.x * 256 + t;
    int x = (i < n) ? v[i] : 0;
    int orig = x;
#pragma unroll
    for (int off = 1; off < 64; off <<= 1) {
        int u = __shfl_up(x, off, 64);
        if (lane >= off) x += u;
    }
    __shared__ int wsh[4];
    if (lane == 63) wsh[wave] = x;
    __syncthreads();
    int wexc = 0;
    for (int w = 0; w < wave; ++w) wexc += wsh[w];
    if (i < n) out[i] = boff[blockIdx.x] + wexc + x - orig;
}

// ---------------- phase C: per-bucket gather + LDS counting sort by node ----------------

__global__ __launch_bounds__(256) void k_fsort(const uint2* __restrict__ tmps,
                                               const int* __restrict__ lscan,
                                               const int* __restrict__ goff,
                                               int* __restrict__ rowptr,
                                               uint2* __restrict__ edata) {
    __shared__ uint2 ent[FCAP];                  // 44 KB
    __shared__ unsigned short perm[FCAP];        // 11 KB
    __shared__ int joff[NBLK + 1];
    __shared__ int jsrc[NBLK];
    __shared__ int hist[256];
    __shared__ int cur[256];
    const int b = blockIdx.x;
    const int t = threadIdx.x;
    const int base = goff[b * NBLK];             // bucket base position in edata

    for (int q = t; q < 256; q += 256) hist[q] = 0;
    for (int j = t; j < NBLK; j += 256) {
        joff[j] = goff[b * NBLK + j] - base;
        jsrc[j] = j * CHUNK + lscan[j * NB + b];
    }
    if (t == 0) joff[NBLK] = ((b == NB - 1) ? NEDGES : goff[(b + 1) * NBLK]) - base;
    __syncthreads();
    const int T = min(joff[NBLK], FCAP);

    for (int idx = t; idx < T; idx += 256) {
        int lo = 0, hi = NBLK;
        while (hi - lo > 1) { int mid = (lo + hi) >> 1; if (joff[mid] <= idx) lo = mid; else hi = mid; }
        const uint2 e = tmps[jsrc[lo] + (idx - joff[lo])];   // piecewise-coalesced
        ent[idx] = e;
        atomicAdd(&hist[(e.x >> 17) & 255u], 1);
    }
    __syncthreads();

    // exclusive scan hist[0..256) -> cur, wave 0 (64 lanes x 4)
    if (t < 64) {
        int x[4];
        int run = 0;
#pragma unroll
        for (int q = 0; q < 4; ++q) { x[q] = hist[t * 4 + q]; run += x[q]; }
        int inc = run;
#pragma unroll
        for (int o = 1; o < 64; o <<= 1) {
            int u = __shfl_up(inc, o, 64);
            if (t >= o) inc += u;
        }
        int r = inc - run;
#pragma unroll
        for (int q = 0; q < 4; ++q) { cur[t * 4 + q] = r; r += x[q]; }
    }
    __syncthreads();

    {
        const int i = b * 256 + t;
        if (i < NNODES) rowptr[i] = base + cur[t];
    }
    __syncthreads();    // rowptr reads of cur must complete before rank mutation

    for (int idx = t; idx < T; idx += 256) {
        const int d = (int)((ent[idx].x >> 17) & 255u);
        const int r = atomicAdd(&cur[d], 1);
        perm[r] = (unsigned short)idx;
    }
    __syncthreads();
    for (int k = t; k < T; k += 256)
        edata[base + k] = ent[perm[k]];          // coalesced global write
}

// ---------------- weight pre-conversion: f32 [K][64] x2 -> f16 col-major [128][K] ----------------

__global__ __launch_bounds__(256) void k_wprep(const float* __restrict__ W1l, const float* __restrict__ W1r,
                                               const float* __restrict__ W2l, const float* __restrict__ W2r,
                                               const float* __restrict__ W3l, const float* __restrict__ W3r,
                                               unsigned short* __restrict__ Wt1,
                                               unsigned short* __restrict__ Wt2,
                                               unsigned short* __restrict__ Wt3) {
    const int idx = blockIdx.x * 256 + threadIdx.x;
    if (idx < 16384) {                            // Wt1: 128 cols x 128 k
        const int c = idx >> 7, k = idx & 127;
        const float v = (c < 64) ? W1l[k * 64 + c] : W1r[k * 64 + (c - 64)];
        Wt1[c * 128 + k] = f16rne(v);
    } else if (idx < 24576) {                     // Wt2: 128 cols x 64 k
        const int j = idx - 16384;
        const int c = j >> 6, k = j & 63;
        const float v = (c < 64) ? W2l[k * 64 + c] : W2r[k * 64 + (c - 64)];
        Wt2[c * 64 + k] = f16rne(v);
    } else if (idx < 32768) {                     // Wt3: 128 cols x 64 k
        const int j = idx - 24576;
        const int c = j >> 6, k = j & 63;
        const float v = (c < 64) ? W3l[k * 64 + c] : W3r[k * 64 + (c - 64)];
        Wt3[c * 64 + k] = f16rne(v);
    }
}

// ---------------- MFMA dual GEMM: [XL|XR] = X @ [Wl|Wr] + bias, f16 in/out ----------------
// Block = 64 rows x 128 cols, full K in LDS. mfma_f32_16x16x32_f16 fragments:
// A: row=lane&15, k=(lane>>4)*8+j; B: col=lane&15, k=(lane>>4)*8+j;
// D: col=lane&15, row=(lane>>4)*4+reg. Row pad +8 halves -> 2-way (free) LDS banks.
// W pre-converted f16 col-major (k_wprep) -> staging is pure uint4 copies.

template <int K, bool F32IN>
__global__ __launch_bounds__(256) void k_gemm_mfma(const void* __restrict__ Xin,
                                                   const unsigned short* __restrict__ Wt,
                                                   const float* __restrict__ bl,
                                                   const float* __restrict__ br,
                                                   unsigned short* __restrict__ XLu,
                                                   unsigned short* __restrict__ XRu) {
    constexpr int KP = K + 8;
    __shared__ unsigned short sA[64 * KP];
    __shared__ unsigned short sB[128 * KP];
    const int t = threadIdx.x;
    const int w = t >> 6, lane = t & 63;
    const int r0 = blockIdx.x * 64;

    // stage B: pure vector copy of pre-converted weights
    {
        const uint4* Wu = (const uint4*)Wt;
#pragma unroll
        for (int idx = t; idx < 128 * (K / 8); idx += 256) {
            const int row = idx / (K / 8), q = idx % (K / 8);
            *(uint4*)&sB[row * KP + q * 8] = Wu[idx];
        }
    }
    // stage A: 64 rows x K
    if constexpr (F32IN) {
        const float* X = (const float*)Xin;
        for (int idx = t; idx < 64 * (K / 4); idx += 256) {
            const int row = idx / (K / 4), q = idx % (K / 4);
            const int rr = min(r0 + row, NNODES - 1);
            const float4 v = *(const float4*)&X[(size_t)rr * K + q * 4];
            unsigned* p = (unsigned*)&sA[row * KP + q * 4];
            p[0] = packh2(v.x, v.y);
            p[1] = packh2(v.z, v.w);
        }
    } else {
        const uint4* X = (const uint4*)Xin;      // packed f16 rows: 8 x uint4
        for (int idx = t; idx < 64 * 8; idx += 256) {
            const int row = idx >> 3, q = idx & 7;
            const int rr = min(r0 + row, NNODES - 1);
            *(uint4*)&sA[row * KP + q * 8] = X[(size_t)rr * 8 + q];
        }
    }
    __syncthreads();

    f32x4 acc[8] = {};
    const int mrow = w * 16 + (lane & 15);
    const int kb = (lane >> 4) * 8;
#pragma unroll
    for (int kc = 0; kc < K / 32; ++kc) {
        const f16x8 af = *(const f16x8*)&sA[mrow * KP + kc * 32 + kb];
#pragma unroll
        for (int nt = 0; nt < 8; ++nt) {
            const f16x8 bfr = *(const f16x8*)&sB[(nt * 16 + (lane & 15)) * KP + kc * 32 + kb];
            acc[nt] = __builtin_amdgcn_mfma_f32_16x16x32_f16(af, bfr, acc[nt], 0, 0, 0);
        }
    }

    // epilogue: bias + f16 store
    const int colL = lane & 15;
    const int rbase = r0 + w * 16 + (lane >> 4) * 4;
#pragma unroll
    for (int nt = 0; nt < 8; ++nt) {
        const int col = nt * 16 + colL;
        const bool isL = col < 64;
        const float bv = isL ? bl[col] : br[col - 64];
        unsigned short* OUT = isL ? XLu : XRu;
        const int oc = isL ? col : col - 64;
#pragma unroll
        for (int r = 0; r < 4; ++r) {
            const int grow = rbase + r;
            if (grow < NNODES)
                OUT[(size_t)grow * 64 + oc] = f16rne(acc[nt][r] + bv);
        }
    }
}

// ---------------- fused GATv2 edge pass (packed-f16 math) ----------------
// One wave per node. lane = 8*group + fl; group g handles edge e+g (8/batch);
// lane holds features [fl*8, fl*8+8) as 4x h2 (f16 pairs) from one uint4.
// Packed-f16 message/dot: pre = pk_fma(ev, We, xr); m = pre + v;
// s1 += pk_fma(0.6att, m); s2 += pk_fma(0.4att, |m|)  [leaky folded].
// Fixed-base softmax (C = self logit, shift-invariant): no max tracking.
// Per-wave LDS combine, stride-65 scalar stores, no block barrier.

__global__ __launch_bounds__(256) void k_edge(const uint4* __restrict__ XLh,
                                              const uint4* __restrict__ XRh,
                                              const int* __restrict__ rowptr,
                                              const uint2* __restrict__ edata,
                                              const float* __restrict__ We,
                                              const float* __restrict__ att,
                                              const float* __restrict__ bias,
                                              const float* __restrict__ easum,
                                              unsigned* __restrict__ Hh) {
    __shared__ float red[4][8][65];              // bank = (g + 8*fl + k) % 32: 2/bank (free)
    const int wave = threadIdx.x >> 6, lane = threadIdx.x & 63;
    const int g = lane >> 3, fl = lane & 7;
    const int fo = fl * 8;
    h2 We2[4], a06[4], a04[4];
#pragma unroll
    for (int k = 0; k < 4; ++k) {
        We2[k] = h2{(_Float16)We[fo + 2 * k], (_Float16)We[fo + 2 * k + 1]};
        a06[k] = h2{(_Float16)(0.6f * att[fo + 2 * k]), (_Float16)(0.6f * att[fo + 2 * k + 1])};
        a04[k] = h2{(_Float16)(0.4f * att[fo + 2 * k]), (_Float16)(0.4f * att[fo + 2 * k + 1])};
    }
    const float bias_l = bias[lane];
    const float ea_mean = easum[0] * (1.0f / NEDGES);

    const int i = blockIdx.x * 4 + wave;         // exact grid: always < NNODES

    h2 xr2[4], xl2[4];
    {
        const uint4 wr = XRh[(size_t)i * 8 + fl];
        __builtin_memcpy(xr2, &wr, 16);
        const uint4 wl = XLh[(size_t)i * 8 + fl];
        __builtin_memcpy(xl2, &wl, 16);
    }

    // self-loop logit (src=i, ea=ea_mean): identical across groups -> wave-uniform
    float M;
    {
        const _Float16 eh = (_Float16)ea_mean;
        const h2 ev2 = h2{eh, eh};
        h2 s1v = h2{(_Float16)0.f, (_Float16)0.f};
        h2 s2v = s1v;
#pragma unroll
        for (int k = 0; k < 4; ++k) {
            const h2 m = __builtin_elementwise_fma(ev2, We2[k], xr2[k]) + xl2[k];
            s1v = __builtin_elementwise_fma(a06[k], m, s1v);
            s2v = __builtin_elementwise_fma(a04[k], habs(m), s2v);
        }
        const h2 sv = s1v + s2v;
        float pt = (float)sv[0] + (float)sv[1];
        pt += __shfl_xor(pt, 1);
        pt += __shfl_xor(pt, 2);
        pt += __shfl_xor(pt, 4);
        M = pt;                                  // fixed softmax base
    }
    float S = (g == 0) ? 1.f : 0.f;              // self-loop: exp(M-M)=1, group 0 only
    float acc8[8];
#pragma unroll
    for (int k = 0; k < 4; ++k) {
        acc8[2 * k] = (g == 0) ? (float)xl2[k][0] : 0.f;
        acc8[2 * k + 1] = (g == 0) ? (float)xl2[k][1] : 0.f;
    }

    const int e0 = rowptr[i];
    const int ne = rowptr[i + 1] - e0;
    const uint2 z2 = make_uint2(0u, 0u);

    uint2 se = (g < ne) ? edata[e0 + g] : z2;    // meta prefetch, 1 batch ahead
    for (int e = 0; e < ne; e += 8) {
        const uint2 se_cur = se;
        const bool valid = (e + g) < ne;
        if (e + 8 + g < ne) se = edata[e0 + e + 8 + g];
        const int s = (int)(se_cur.x & 0x1FFFFu);
        const float eav = __uint_as_float(se_cur.y);
        const uint4 wv = XLh[(size_t)s * 8 + fl];
        h2 v2[4];
        __builtin_memcpy(v2, &wv, 16);
        const _Float16 eh = (_Float16)eav;
        const h2 ev2 = h2{eh, eh};

        h2 s1v = h2{(_Float16)0.f, (_Float16)0.f};
        h2 s2v = s1v;
#pragma unroll
        for (int k = 0; k < 4; ++k) {
            const h2 m = __builtin_elementwise_fma(ev2, We2[k], xr2[k]) + v2[k];
            s1v = __builtin_elementwise_fma(a06[k], m, s1v);
            s2v = __builtin_elementwise_fma(a04[k], habs(m), s2v);
        }
        const h2 sv = s1v + s2v;
        float d = (float)sv[0] + (float)sv[1];
        d += __shfl_xor(d, 1);
        d += __shfl_xor(d, 2);
        d += __shfl_xor(d, 4);                   // group-uniform logit
        const float a = valid ? d : -1e30f;      // exp(-inf)=0 for pad groups

        const float p = __expf(a - M);           // fixed base: no max tracking
        S += p;                                  // group-partial (deferred reduce)
#pragma unroll
        for (int k = 0; k < 4; ++k) {
            acc8[2 * k] = fmaf(p, (float)v2[k][0], acc8[2 * k]);
            acc8[2 * k + 1] = fmaf(p, (float)v2[k][1], acc8[2 * k + 1]);
        }
    }

    // reduce S across groups (xor 8/16/32 touches g bits only)
    S += __shfl_xor(S, 8);
    S += __shfl_xor(S, 16);
    S += __shfl_xor(S, 32);

    // per-wave LDS transpose-combine (no inter-wave sharing -> no block barrier)
#pragma unroll
    for (int k = 0; k < 8; ++k) red[wave][g][fo + k] = acc8[k];
    asm volatile("" ::: "memory");
    __builtin_amdgcn_wave_barrier();             // DS ops complete in-order per wave
    float o = 0.f;
#pragma unroll
    for (int gg = 0; gg < 8; ++gg) o += red[wave][gg][lane];
    o = fmaxf(o / S + bias_l, 0.f);              // bias + fused ReLU
    const float on = __shfl_xor(o, 1);
    if (!(lane & 1))
        Hh[(size_t)i * 32 + (lane >> 1)] = packh2(o, on);   // packed f16 store
}

// ---------------- tail: mean pool + linear + softmax ----------------

__global__ __launch_bounds__(256) void k_colsum(const unsigned* __restrict__ Hh,
                                                float* __restrict__ gsum) {
    const int t = threadIdx.x;
    const int c = t & 31;                        // uint column = feature pair
    const int rl = t >> 5;                       // 0..7
    float s0 = 0.f, s1 = 0.f;
    for (int r = blockIdx.x * 8 + rl; r < NNODES; r += gridDim.x * 8) {
        const unsigned u = Hh[(size_t)r * 32 + c];
        h2 hv;
        __builtin_memcpy(&hv, &u, 4);
        s0 += (float)hv[0];
        s1 += (float)hv[1];
    }
    __shared__ float ls[8][64];
    ls[rl][2 * c] = s0;
    ls[rl][2 * c + 1] = s1;
    __syncthreads();
    if (t < 64) {
        float s = 0.f;
#pragma unroll
        for (int q = 0; q < 8; ++q) s += ls[q][t];
        atomicAdd(&gsum[t], s);
    }
}

__global__ __launch_bounds__(64) void k_head(const float* __restrict__ gsum,
                                             const float* __restrict__ Wlin,
                                             const float* __restrict__ blin,
                                             float* __restrict__ out) {
    int lane = threadIdx.x;
    float g = gsum[lane] * (1.0f / NNODES);
    float a0 = wave_sum64(g * Wlin[lane * 2 + 0]);
    float a1 = wave_sum64(g * Wlin[lane * 2 + 1]);
    if (lane == 0) {
        float l0 = a0 + blin[0], l1 = a1 + blin[1];
        float mx = fmaxf(l0, l1);
        float e0 = __expf(l0 - mx), e1 = __expf(l1 - mx);
        float inv = 1.f / (e0 + e1);
        out[0] = e0 * inv;
        out[1] = e1 * inv;
    }
}

extern "C" void kernel_launch(void* const* d_in, const int* in_sizes, int n_in,
                              void* d_out, int out_size, void* d_ws, size_t ws_size,
                              hipStream_t stream) {
    const float* x = (const float*)d_in[0];
    const int* ei = (const int*)d_in[1];
    const float* ea = (const float*)d_in[2];
    const int* src = ei;
    const int* dst = ei + NEDGES;
    auto W = [&](int i) { return (const float*)d_in[i]; };

    char* ws = (char*)d_ws;
    size_t off = 0;
    auto alloc = [&](size_t bytes) {
        void* p = ws + off;
        off += (bytes + 255) & ~(size_t)255;
        return p;
    };
    unsigned short* XLu = (unsigned short*)alloc((size_t)NNODES * 64 * 2);  // packed f16
    unsigned short* XRu = (unsigned short*)alloc((size_t)NNODES * 64 * 2);  // packed f16
    unsigned* Hh = (unsigned*)alloc((size_t)NBLK * CHUNK * 8);  // 12.82 MB: packed f16 H, aliased by tmps
    int* rowptr = (int*)alloc((size_t)(NNODES + 1) * 4);
    uint2* edata = (uint2*)alloc((size_t)NEDGES * 8);
    float* easum = (float*)alloc(4);
    float* gsum = (float*)alloc(64 * 4);
    int* gcnt = (int*)alloc((size_t)FLATN * 4);
    int* lscan = (int*)alloc((size_t)FLATN * 4);
    int* goff = (int*)alloc((size_t)FLATN * 4);
    int* part2 = (int*)alloc((size_t)SCB * 4);
    int* boff2 = (int*)alloc((size_t)SCB * 4);
    unsigned short* Wt1 = (unsigned short*)alloc(16384 * 2);
    unsigned short* Wt2 = (unsigned short*)alloc(8192 * 2);
    unsigned short* Wt3 = (unsigned short*)alloc(8192 * 2);
    uint2* tmps = (uint2*)Hh;  // Hh dead until layer-1 k_edge; sort uses it first

    hipMemsetAsync(easum, 0, 4, stream);
    hipMemsetAsync(gsum, 0, 64 * 4, stream);

    k_wprep<<<128, 256, 0, stream>>>(W(3), W(5), W(10), W(12), W(17), W(19), Wt1, Wt2, Wt3);
    k_lsort<<<NBLK, 256, 0, stream>>>(src, dst, ea, tmps, gcnt, lscan, easum);
    k_part2<<<SCB, 256, 0, stream>>>(gcnt, FLATN, part2);
    k_scanb2<<<1, 1024, 0, stream>>>(part2, SCB, boff2, rowptr);
    k_scanfin2<<<SCB, 256, 0, stream>>>(gcnt, FLATN, boff2, goff);
    k_fsort<<<NB, 256, 0, stream>>>(tmps, lscan, goff, rowptr, edata);

    int gemm_grid = (NNODES + 63) / 64;   // 1563
    int edge_grid = NNODES / 4;           // exact: one wave per node

    k_gemm_mfma<128, true><<<gemm_grid, 256, 0, stream>>>(x, Wt1, W(4), W(6), XLu, XRu);
    k_edge<<<edge_grid, 256, 0, stream>>>((const uint4*)XLu, (const uint4*)XRu, rowptr, edata,
                                          W(7), W(8), W(9), easum, Hh);
    k_gemm_mfma<64, false><<<gemm_grid, 256, 0, stream>>>(Hh, Wt2, W(11), W(13), XLu, XRu);
    k_edge<<<edge_grid, 256, 0, stream>>>((const uint4*)XLu, (const uint4*)XRu, rowptr, edata,
                                          W(14), W(15), W(16), easum, Hh);
    k_gemm_mfma<64, false><<<gemm_grid, 256, 0, stream>>>(Hh, Wt3, W(18), W(20), XLu, XRu);
    k_edge<<<edge_grid, 256, 0, stream>>>((const uint4*)XLu, (const uint4*)XRu, rowptr, edata,
                                          W(21), W(22), W(23), easum, Hh);

    k_colsum<<<256, 256, 0, stream>>>(Hh, gsum);
    k_head<<<1, 64, 0, stream>>>(gsum, W(24), W(25), (float*)d_out);
}

// Round 16
// 293.168 us; speedup vs baseline: 1.3018x; 1.0132x over previous
//
#include <hip/hip_runtime.h>
#include <hip/hip_bf16.h>

#define NNODES 100000
#define NEDGES 1600000
#define NEG_SLOPE 0.2f

#define CHUNK 4096
#define EPT 16                                  // edges per thread in k_lsort
#define NBLK ((NEDGES + CHUNK - 1) / CHUNK)     // 391 sort blocks
#define NB ((NNODES + 255) / 256)               // 391 buckets (256 nodes each)
#define FLATN (NB * NBLK)                       // 152881
#define SCB ((FLATN + 255) / 256)               // 598
#define FCAP 5632                               // bucket entry cap (mean 4092, +24 sigma)

typedef __attribute__((ext_vector_type(8))) _Float16 f16x8;
typedef __attribute__((ext_vector_type(2))) _Float16 h2;
typedef __attribute__((ext_vector_type(4))) float f32x4;

__device__ __forceinline__ float wave_sum64(float v) {
#pragma unroll
    for (int off = 1; off < 64; off <<= 1) v += __shfl_xor(v, off, 64);
    return v;
}

__device__ __forceinline__ int wave_sum64i(int v) {
#pragma unroll
    for (int off = 1; off < 64; off <<= 1) v += __shfl_xor(v, off, 64);
    return v;
}

// f32 -> f16 bits (RNE per IEEE conversion semantics)
__device__ __forceinline__ unsigned short f16rne(float a) {
    _Float16 h = (_Float16)a;
    unsigned short u;
    __builtin_memcpy(&u, &h, 2);
    return u;
}

// pack two f32 -> one uint of 2 f16
__device__ __forceinline__ unsigned packh2(float a, float b) {
    h2 v = {(_Float16)a, (_Float16)b};
    unsigned u;
    __builtin_memcpy(&u, &v, 4);
    return u;
}

__device__ __forceinline__ h2 habs(h2 x) {
    unsigned u;
    __builtin_memcpy(&u, &x, 4);
    u &= 0x7FFF7FFFu;
    h2 r;
    __builtin_memcpy(&r, &u, 4);
    return r;
}

// ---------------- phase A: per-chunk counting sort by bucket (all-coalesced) ----------------

__global__ __launch_bounds__(256) void k_lsort(const int* __restrict__ src,
                                               const int* __restrict__ dst,
                                               const float* __restrict__ ea,
                                               uint2* __restrict__ tmps,
                                               int* __restrict__ gcnt,
                                               int* __restrict__ lscan,
                                               float* __restrict__ easum) {
    __shared__ uint2 ent[CHUNK];                 // 32 KB
    __shared__ unsigned short perm[CHUNK];       // 8 KB
    __shared__ int hist[NB];
    __shared__ int cur[NB];
    __shared__ float ws[4];
    const int t = threadIdx.x;
    const int j = blockIdx.x;
    const int base = j * CHUNK;
    const int n = min(CHUNK, NEDGES - base);

    for (int b = t; b < NB; b += 256) hist[b] = 0;
    __syncthreads();

    int bkt[EPT];
    float s = 0.f;
#pragma unroll
    for (int k = 0; k < EPT; ++k) {
        const int l = t + k * 256;
        bkt[k] = -1;
        if (l < n) {
            const int i = base + l;
            const int d = dst[i];
            const float e = ea[i];
            const int b = d >> 8;
            bkt[k] = b;
            ent[l] = make_uint2((unsigned)src[i] | ((unsigned)(d & 255) << 17),
                                __float_as_uint(e));
            atomicAdd(&hist[b], 1);
            s += e;
        }
    }
    s = wave_sum64(s);
    if ((t & 63) == 0) ws[t >> 6] = s;
    __syncthreads();
    if (t == 0) atomicAdd(easum, ws[0] + ws[1] + ws[2] + ws[3]);

    // exclusive scan of hist[0..NB) -> cur, wave 0 only (56 lanes x 7 elems)
    if (t < 64) {
        int x[7];
        int run = 0;
#pragma unroll
        for (int q = 0; q < 7; ++q) {
            const int idx = t * 7 + q;
            x[q] = (idx < NB) ? hist[idx] : 0;
            run += x[q];
        }
        int inc = run;
#pragma unroll
        for (int o = 1; o < 64; o <<= 1) {
            int u = __shfl_up(inc, o, 64);
            if (t >= o) inc += u;
        }
        int r = inc - run;   // lane-exclusive
#pragma unroll
        for (int q = 0; q < 7; ++q) {
            const int idx = t * 7 + q;
            if (idx < NB) cur[idx] = r;
            r += x[q];
        }
    }
    __syncthreads();

#pragma unroll
    for (int k = 0; k < EPT; ++k) {
        if (bkt[k] >= 0) {
            const int r = atomicAdd(&cur[bkt[k]], 1);
            perm[r] = (unsigned short)(t + k * 256);
        }
    }
    __syncthreads();

    for (int o = t; o < n; o += 256)
        tmps[base + o] = ent[perm[o]];           // coalesced global write
    for (int b = t; b < NB; b += 256) {
        gcnt[b * NBLK + j] = hist[b];            // bucket-major (for flat scan)
        lscan[j * NB + b] = cur[b] - hist[b];    // local exclusive offset
    }
}

// ---------------- flat exclusive scan of gcnt[FLATN] -> goff ----------------

__global__ __launch_bounds__(256) void k_part2(const int* __restrict__ v, int n,
                                               int* __restrict__ bsum) {
    int i = blockIdx.x * 256 + threadIdx.x;
    int x = (i < n) ? v[i] : 0;
    x = wave_sum64i(x);
    __shared__ int wsh[4];
    if ((threadIdx.x & 63) == 0) wsh[threadIdx.x >> 6] = x;
    __syncthreads();
    if (threadIdx.x == 0) bsum[blockIdx.x] = wsh[0] + wsh[1] + wsh[2] + wsh[3];
}

__global__ __launch_bounds__(1024) void k_scanb2(const int* __restrict__ bsum, int nb,
                                                 int* __restrict__ boff,
                                                 int* __restrict__ rowptr) {
    __shared__ int sh[1024];
    int t = threadIdx.x;
    int v = (t < nb) ? bsum[t] : 0;
    sh[t] = v;
    __syncthreads();
    for (int off = 1; off < 1024; off <<= 1) {
        int u = (t >= off) ? sh[t - off] : 0;
        __syncthreads();
        sh[t] += u;
        __syncthreads();
    }
    if (t < nb) boff[t] = sh[t] - v;
    if (t == 0) rowptr[NNODES] = NEDGES;
}

__global__ __launch_bounds__(256) void k_scanfin2(const int* __restrict__ v, int n,
                                                  const int* __restrict__ boff,
                                                  int* __restrict__ out) {
    int t = threadIdx.x, lane = t & 63, wave = t >> 6;
    int i = blockIdx.x * 256 + t;
    int x = (i < n) ? v[i] : 0;
    int orig = x;
#pragma unroll
    for (int off = 1; off < 64; off <<= 1) {
        int u = __shfl_up(x, off, 64);
        if (lane >= off) x += u;
    }
    __shared__ int wsh[4];
    if (lane == 63) wsh[wave] = x;
    __syncthreads();
    int wexc = 0;
    for (int w = 0; w < wave; ++w) wexc += wsh[w];
    if (i < n) out[i] = boff[blockIdx.x] + wexc + x - orig;
}

// ---------------- phase C: per-bucket gather + LDS counting sort by node ----------------

__global__ __launch_bounds__(256) void k_fsort(const uint2* __restrict__ tmps,
                                               const int* __restrict__ lscan,
                                               const int* __restrict__ goff,
                                               int* __restrict__ rowptr,
                                               uint2* __restrict__ edata) {
    __shared__ uint2 ent[FCAP];                  // 44 KB
    __shared__ unsigned short perm[FCAP];        // 11 KB
    __shared__ int joff[NBLK + 1];
    __shared__ int jsrc[NBLK];
    __shared__ int hist[256];
    __shared__ int cur[256];
    const int b = blockIdx.x;
    const int t = threadIdx.x;
    const int base = goff[b * NBLK];             // bucket base position in edata

    for (int q = t; q < 256; q += 256) hist[q] = 0;
    for (int j = t; j < NBLK; j += 256) {
        joff[j] = goff[b * NBLK + j] - base;
        jsrc[j] = j * CHUNK + lscan[j * NB + b];
    }
    if (t == 0) joff[NBLK] = ((b == NB - 1) ? NEDGES : goff[(b + 1) * NBLK]) - base;
    __syncthreads();
    const int T = min(joff[NBLK], FCAP);

    for (int idx = t; idx < T; idx += 256) {
        int lo = 0, hi = NBLK;
        while (hi - lo > 1) { int mid = (lo + hi) >> 1; if (joff[mid] <= idx) lo = mid; else hi = mid; }
        const uint2 e = tmps[jsrc[lo] + (idx - joff[lo])];   // piecewise-coalesced
        ent[idx] = e;
        atomicAdd(&hist[(e.x >> 17) & 255u], 1);
    }
    __syncthreads();

    // exclusive scan hist[0..256) -> cur, wave 0 (64 lanes x 4)
    if (t < 64) {
        int x[4];
        int run = 0;
#pragma unroll
        for (int q = 0; q < 4; ++q) { x[q] = hist[t * 4 + q]; run += x[q]; }
        int inc = run;
#pragma unroll
        for (int o = 1; o < 64; o <<= 1) {
            int u = __shfl_up(inc, o, 64);
            if (t >= o) inc += u;
        }
        int r = inc - run;
#pragma unroll
        for (int q = 0; q < 4; ++q) { cur[t * 4 + q] = r; r += x[q]; }
    }
    __syncthreads();

    {
        const int i = b * 256 + t;
        if (i < NNODES) rowptr[i] = base + cur[t];
    }
    __syncthreads();    // rowptr reads of cur must complete before rank mutation

    for (int idx = t; idx < T; idx += 256) {
        const int d = (int)((ent[idx].x >> 17) & 255u);
        const int r = atomicAdd(&cur[d], 1);
        perm[r] = (unsigned short)idx;
    }
    __syncthreads();
    for (int k = t; k < T; k += 256)
        edata[base + k] = ent[perm[k]];          // coalesced global write
}

// ---------------- weight/param pre-conversion ----------------
// Wt*: f32 [K][64] x2 -> f16 col-major [128][K] for MFMA staging.
// epar: per layer 96 dwords = h2 We[32] | h2 0.6*att[32] | h2 0.4*att[32].

__global__ __launch_bounds__(256) void k_wprep(const float* __restrict__ W1l, const float* __restrict__ W1r,
                                               const float* __restrict__ W2l, const float* __restrict__ W2r,
                                               const float* __restrict__ W3l, const float* __restrict__ W3r,
                                               const float* __restrict__ We1, const float* __restrict__ att1,
                                               const float* __restrict__ We2, const float* __restrict__ att2,
                                               const float* __restrict__ We3, const float* __restrict__ att3,
                                               unsigned short* __restrict__ Wt1,
                                               unsigned short* __restrict__ Wt2,
                                               unsigned short* __restrict__ Wt3,
                                               unsigned* __restrict__ epar) {
    const int idx = blockIdx.x * 256 + threadIdx.x;
    if (idx < 16384) {                            // Wt1: 128 cols x 128 k
        const int c = idx >> 7, k = idx & 127;
        const float v = (c < 64) ? W1l[k * 64 + c] : W1r[k * 64 + (c - 64)];
        Wt1[c * 128 + k] = f16rne(v);
    } else if (idx < 24576) {                     // Wt2: 128 cols x 64 k
        const int j = idx - 16384;
        const int c = j >> 6, k = j & 63;
        const float v = (c < 64) ? W2l[k * 64 + c] : W2r[k * 64 + (c - 64)];
        Wt2[c * 64 + k] = f16rne(v);
    } else if (idx < 32768) {                     // Wt3: 128 cols x 64 k
        const int j = idx - 24576;
        const int c = j >> 6, k = j & 63;
        const float v = (c < 64) ? W3l[k * 64 + c] : W3r[k * 64 + (c - 64)];
        Wt3[c * 64 + k] = f16rne(v);
    } else if (idx < 32768 + 288) {               // epar: 3 layers x 3 arrays x 32 h2
        const int j = idx - 32768;
        const int layer = j / 96, rem = j % 96;
        const int arr = rem >> 5, q = rem & 31;
        const float* We = (layer == 0) ? We1 : (layer == 1) ? We2 : We3;
        const float* at = (layer == 0) ? att1 : (layer == 1) ? att2 : att3;
        float a, b;
        if (arr == 0)      { a = We[2 * q];          b = We[2 * q + 1]; }
        else if (arr == 1) { a = 0.6f * at[2 * q];   b = 0.6f * at[2 * q + 1]; }
        else               { a = 0.4f * at[2 * q];   b = 0.4f * at[2 * q + 1]; }
        epar[layer * 96 + arr * 32 + q] = packh2(a, b);
    }
}

// ---------------- MFMA dual GEMM: [XL|XR] = X @ [Wl|Wr] + bias, f16 in/out ----------------

template <int K, bool F32IN>
__global__ __launch_bounds__(256) void k_gemm_mfma(const void* __restrict__ Xin,
                                                   const unsigned short* __restrict__ Wt,
                                                   const float* __restrict__ bl,
                                                   const float* __restrict__ br,
                                                   unsigned short* __restrict__ XLu,
                                                   unsigned short* __restrict__ XRu) {
    constexpr int KP = K + 8;
    __shared__ unsigned short sA[64 * KP];
    __shared__ unsigned short sB[128 * KP];
    const int t = threadIdx.x;
    const int w = t >> 6, lane = t & 63;
    const int r0 = blockIdx.x * 64;

    {
        const uint4* Wu = (const uint4*)Wt;
#pragma unroll
        for (int idx = t; idx < 128 * (K / 8); idx += 256) {
            const int row = idx / (K / 8), q = idx % (K / 8);
            *(uint4*)&sB[row * KP + q * 8] = Wu[idx];
        }
    }
    if constexpr (F32IN) {
        const float* X = (const float*)Xin;
        for (int idx = t; idx < 64 * (K / 4); idx += 256) {
            const int row = idx / (K / 4), q = idx % (K / 4);
            const int rr = min(r0 + row, NNODES - 1);
            const float4 v = *(const float4*)&X[(size_t)rr * K + q * 4];
            unsigned* p = (unsigned*)&sA[row * KP + q * 4];
            p[0] = packh2(v.x, v.y);
            p[1] = packh2(v.z, v.w);
        }
    } else {
        const uint4* X = (const uint4*)Xin;      // packed f16 rows: 8 x uint4
        for (int idx = t; idx < 64 * 8; idx += 256) {
            const int row = idx >> 3, q = idx & 7;
            const int rr = min(r0 + row, NNODES - 1);
            *(uint4*)&sA[row * KP + q * 8] = X[(size_t)rr * 8 + q];
        }
    }
    __syncthreads();

    f32x4 acc[8] = {};
    const int mrow = w * 16 + (lane & 15);
    const int kb = (lane >> 4) * 8;
#pragma unroll
    for (int kc = 0; kc < K / 32; ++kc) {
        const f16x8 af = *(const f16x8*)&sA[mrow * KP + kc * 32 + kb];
#pragma unroll
        for (int nt = 0; nt < 8; ++nt) {
            const f16x8 bfr = *(const f16x8*)&sB[(nt * 16 + (lane & 15)) * KP + kc * 32 + kb];
            acc[nt] = __builtin_amdgcn_mfma_f32_16x16x32_f16(af, bfr, acc[nt], 0, 0, 0);
        }
    }

    const int colL = lane & 15;
    const int rbase = r0 + w * 16 + (lane >> 4) * 4;
#pragma unroll
    for (int nt = 0; nt < 8; ++nt) {
        const int col = nt * 16 + colL;
        const bool isL = col < 64;
        const float bv = isL ? bl[col] : br[col - 64];
        unsigned short* OUT = isL ? XLu : XRu;
        const int oc = isL ? col : col - 64;
#pragma unroll
        for (int r = 0; r < 4; ++r) {
            const int grow = rbase + r;
            if (grow < NNODES)
                OUT[(size_t)grow * 64 + oc] = f16rne(acc[nt][r] + bv);
        }
    }
}

// ---------------- fused GATv2 edge pass (packed-f16, 4 nodes per wave) ----------------
// Wave loops over 4 consecutive nodes; constants (We/0.6att/0.4att packs via
// epar, bias, easum) loaded once per wave. lane = 8*group + fl; group g handles
// edge e+g (8/batch); lane holds features [fl*8,fl*8+8) as 4x h2 from one uint4.
// Fixed-base softmax (C = self logit). Per-wave LDS combine, no block barrier.

__global__ __launch_bounds__(256) void k_edge(const uint4* __restrict__ XLh,
                                              const uint4* __restrict__ XRh,
                                              const int* __restrict__ rowptr,
                                              const uint2* __restrict__ edata,
                                              const unsigned* __restrict__ epar,
                                              const float* __restrict__ bias,
                                              const float* __restrict__ easum,
                                              unsigned* __restrict__ Hh) {
    __shared__ float red[4][8][65];              // bank = (g + 8*fl + k) % 32: 2/bank (free)
    const int wave = threadIdx.x >> 6, lane = threadIdx.x & 63;
    const int g = lane >> 3, fl = lane & 7;
    const int fo = fl * 8;

    h2 We2[4], a06[4], a04[4];
    {
        const uint4 wu = ((const uint4*)epar)[fl];
        const uint4 u6 = ((const uint4*)(epar + 32))[fl];
        const uint4 u4 = ((const uint4*)(epar + 64))[fl];
        __builtin_memcpy(We2, &wu, 16);
        __builtin_memcpy(a06, &u6, 16);
        __builtin_memcpy(a04, &u4, 16);
    }
    const float bias_l = bias[lane];
    const float ea_mean = easum[0] * (1.0f / NEDGES);
    const _Float16 eh_mean = (_Float16)ea_mean;
    const h2 evm = h2{eh_mean, eh_mean};
    const uint2 z2 = make_uint2(0u, 0u);

    const int i0 = (blockIdx.x * 4 + wave) * 4;  // 4 consecutive nodes per wave

    for (int ii = 0; ii < 4; ++ii) {
        const int i = i0 + ii;                   // NNODES % 16 == 0: always valid

        h2 xr2[4], xl2[4];
        {
            const uint4 wr = XRh[(size_t)i * 8 + fl];
            __builtin_memcpy(xr2, &wr, 16);
            const uint4 wl = XLh[(size_t)i * 8 + fl];
            __builtin_memcpy(xl2, &wl, 16);
        }

        // self-loop logit: identical across groups -> wave-uniform after reduce
        float M;
        {
            h2 s1v = h2{(_Float16)0.f, (_Float16)0.f};
            h2 s2v = s1v;
#pragma unroll
            for (int k = 0; k < 4; ++k) {
                const h2 m = __builtin_elementwise_fma(evm, We2[k], xr2[k]) + xl2[k];
                s1v = __builtin_elementwise_fma(a06[k], m, s1v);
                s2v = __builtin_elementwise_fma(a04[k], habs(m), s2v);
            }
            const h2 sv = s1v + s2v;
            float pt = (float)sv[0] + (float)sv[1];
            pt += __shfl_xor(pt, 1);
            pt += __shfl_xor(pt, 2);
            pt += __shfl_xor(pt, 4);
            M = pt;                              // fixed softmax base
        }
        float S = (g == 0) ? 1.f : 0.f;          // self-loop: exp(M-M)=1, group 0 only
        float acc8[8];
#pragma unroll
        for (int k = 0; k < 4; ++k) {
            acc8[2 * k] = (g == 0) ? (float)xl2[k][0] : 0.f;
            acc8[2 * k + 1] = (g == 0) ? (float)xl2[k][1] : 0.f;
        }

        const int e0 = rowptr[i];
        const int ne = rowptr[i + 1] - e0;

        uint2 se = (g < ne) ? edata[e0 + g] : z2;    // meta prefetch, 1 batch ahead
        for (int e = 0; e < ne; e += 8) {
            const uint2 se_cur = se;
            const bool valid = (e + g) < ne;
            if (e + 8 + g < ne) se = edata[e0 + e + 8 + g];
            const int s = (int)(se_cur.x & 0x1FFFFu);
            const float eav = __uint_as_float(se_cur.y);
            const uint4 wv = XLh[(size_t)s * 8 + fl];
            h2 v2[4];
            __builtin_memcpy(v2, &wv, 16);
            const _Float16 eh = (_Float16)eav;
            const h2 ev2 = h2{eh, eh};

            h2 s1v = h2{(_Float16)0.f, (_Float16)0.f};
            h2 s2v = s1v;
#pragma unroll
            for (int k = 0; k < 4; ++k) {
                const h2 m = __builtin_elementwise_fma(ev2, We2[k], xr2[k]) + v2[k];
                s1v = __builtin_elementwise_fma(a06[k], m, s1v);
                s2v = __builtin_elementwise_fma(a04[k], habs(m), s2v);
            }
            const h2 sv = s1v + s2v;
            float d = (float)sv[0] + (float)sv[1];
            d += __shfl_xor(d, 1);
            d += __shfl_xor(d, 2);
            d += __shfl_xor(d, 4);               // group-uniform logit
            const float a = valid ? d : -1e30f;  // exp(-inf)=0 for pad groups

            const float p = __expf(a - M);       // fixed base: no max tracking
            S += p;                              // group-partial (deferred reduce)
#pragma unroll
            for (int k = 0; k < 4; ++k) {
                acc8[2 * k] = fmaf(p, (float)v2[k][0], acc8[2 * k]);
                acc8[2 * k + 1] = fmaf(p, (float)v2[k][1], acc8[2 * k + 1]);
            }
        }

        // reduce S across groups (xor 8/16/32 touches g bits only)
        S += __shfl_xor(S, 8);
        S += __shfl_xor(S, 16);
        S += __shfl_xor(S, 32);

        // per-wave LDS transpose-combine (no inter-wave sharing -> no block barrier)
#pragma unroll
        for (int k = 0; k < 8; ++k) red[wave][g][fo + k] = acc8[k];
        asm volatile("" ::: "memory");
        __builtin_amdgcn_wave_barrier();         // DS ops complete in-order per wave
        float o = 0.f;
#pragma unroll
        for (int gg = 0; gg < 8; ++gg) o += red[wave][gg][lane];
        __builtin_amdgcn_wave_barrier();         // reads done before next iter's writes
        o = fmaxf(o / S + bias_l, 0.f);          // bias + fused ReLU
        const float on = __shfl_xor(o, 1);
        if (!(lane & 1))
            Hh[(size_t)i * 32 + (lane >> 1)] = packh2(o, on);   // packed f16 store
    }
}

// ---------------- tail: mean pool + linear + softmax ----------------

__global__ __launch_bounds__(256) void k_colsum(const unsigned* __restrict__ Hh,
                                                float* __restrict__ gsum) {
    const int t = threadIdx.x;
    const int c = t & 31;                        // uint column = feature pair
    const int rl = t >> 5;                       // 0..7
    float s0 = 0.f, s1 = 0.f;
    for (int r = blockIdx.x * 8 + rl; r < NNODES; r += gridDim.x * 8) {
        const unsigned u = Hh[(size_t)r * 32 + c];
        h2 hv;
        __builtin_memcpy(&hv, &u, 4);
        s0 += (float)hv[0];
        s1 += (float)hv[1];
    }
    __shared__ float ls[8][64];
    ls[rl][2 * c] = s0;
    ls[rl][2 * c + 1] = s1;
    __syncthreads();
    if (t < 64) {
        float s = 0.f;
#pragma unroll
        for (int q = 0; q < 8; ++q) s += ls[q][t];
        atomicAdd(&gsum[t], s);
    }
}

__global__ __launch_bounds__(64) void k_head(const float* __restrict__ gsum,
                                             const float* __restrict__ Wlin,
                                             const float* __restrict__ blin,
                                             float* __restrict__ out) {
    int lane = threadIdx.x;
    float g = gsum[lane] * (1.0f / NNODES);
    float a0 = wave_sum64(g * Wlin[lane * 2 + 0]);
    float a1 = wave_sum64(g * Wlin[lane * 2 + 1]);
    if (lane == 0) {
        float l0 = a0 + blin[0], l1 = a1 + blin[1];
        float mx = fmaxf(l0, l1);
        float e0 = __expf(l0 - mx), e1 = __expf(l1 - mx);
        float inv = 1.f / (e0 + e1);
        out[0] = e0 * inv;
        out[1] = e1 * inv;
    }
}

extern "C" void kernel_launch(void* const* d_in, const int* in_sizes, int n_in,
                              void* d_out, int out_size, void* d_ws, size_t ws_size,
                              hipStream_t stream) {
    const float* x = (const float*)d_in[0];
    const int* ei = (const int*)d_in[1];
    const float* ea = (const float*)d_in[2];
    const int* src = ei;
    const int* dst = ei + NEDGES;
    auto W = [&](int i) { return (const float*)d_in[i]; };

    char* ws = (char*)d_ws;
    size_t off = 0;
    auto alloc = [&](size_t bytes) {
        void* p = ws + off;
        off += (bytes + 255) & ~(size_t)255;
        return p;
    };
    unsigned short* XLu = (unsigned short*)alloc((size_t)NNODES * 64 * 2);  // packed f16
    unsigned short* XRu = (unsigned short*)alloc((size_t)NNODES * 64 * 2);  // packed f16
    unsigned* Hh = (unsigned*)alloc((size_t)NBLK * CHUNK * 8);  // 12.82 MB: packed f16 H, aliased by tmps
    int* rowptr = (int*)alloc((size_t)(NNODES + 1) * 4);
    uint2* edata = (uint2*)alloc((size_t)NEDGES * 8);
    float* easum = (float*)alloc(4);
    float* gsum = (float*)alloc(64 * 4);
    int* gcnt = (int*)alloc((size_t)FLATN * 4);
    int* lscan = (int*)alloc((size_t)FLATN * 4);
    int* goff = (int*)alloc((size_t)FLATN * 4);
    int* part2 = (int*)alloc((size_t)SCB * 4);
    int* boff2 = (int*)alloc((size_t)SCB * 4);
    unsigned short* Wt1 = (unsigned short*)alloc(16384 * 2);
    unsigned short* Wt2 = (unsigned short*)alloc(8192 * 2);
    unsigned short* Wt3 = (unsigned short*)alloc(8192 * 2);
    unsigned* epar = (unsigned*)alloc(288 * 4);  // 3 layers x {We,0.6att,0.4att} h2 packs
    uint2* tmps = (uint2*)Hh;  // Hh dead until layer-1 k_edge; sort uses it first

    hipMemsetAsync(easum, 0, 4, stream);
    hipMemsetAsync(gsum, 0, 64 * 4, stream);

    k_wprep<<<130, 256, 0, stream>>>(W(3), W(5), W(10), W(12), W(17), W(19),
                                     W(7), W(8), W(14), W(15), W(21), W(22),
                                     Wt1, Wt2, Wt3, epar);
    k_lsort<<<NBLK, 256, 0, stream>>>(src, dst, ea, tmps, gcnt, lscan, easum);
    k_part2<<<SCB, 256, 0, stream>>>(gcnt, FLATN, part2);
    k_scanb2<<<1, 1024, 0, stream>>>(part2, SCB, boff2, rowptr);
    k_scanfin2<<<SCB, 256, 0, stream>>>(gcnt, FLATN, boff2, goff);
    k_fsort<<<NB, 256, 0, stream>>>(tmps, lscan, goff, rowptr, edata);

    int gemm_grid = (NNODES + 63) / 64;   // 1563
    int edge_grid = NNODES / 16;          // 6250: 4 waves/block x 4 nodes/wave

    k_gemm_mfma<128, true><<<gemm_grid, 256, 0, stream>>>(x, Wt1, W(4), W(6), XLu, XRu);
    k_edge<<<edge_grid, 256, 0, stream>>>((const uint4*)XLu, (const uint4*)XRu, rowptr, edata,
                                          epar, W(9), easum, Hh);
    k_gemm_mfma<64, false><<<gemm_grid, 256, 0, stream>>>(Hh, Wt2, W(11), W(13), XLu, XRu);
    k_edge<<<edge_grid, 256, 0, stream>>>((const uint4*)XLu, (const uint4*)XRu, rowptr, edata,
                                          epar + 96, W(16), easum, Hh);
    k_gemm_mfma<64, false><<<gemm_grid, 256, 0, stream>>>(Hh, Wt3, W(18), W(20), XLu, XRu);
    k_edge<<<edge_grid, 256, 0, stream>>>((const uint4*)XLu, (const uint4*)XRu, rowptr, edata,
                                          epar + 192, W(23), easum, Hh);

    k_colsum<<<256, 256, 0, stream>>>(Hh, gsum);
    k_head<<<1, 64, 0, stream>>>(gsum, W(24), W(25), (float*)d_out);
}

// Round 17
// 289.440 us; speedup vs baseline: 1.3185x; 1.0129x over previous
//
#include <hip/hip_runtime.h>
#include <hip/hip_bf16.h>

#define NNODES 100000
#define NEDGES 1600000
#define NEG_SLOPE 0.2f

#define CHUNK 4096
#define EPT 16                                  // edges per thread in k_lsort
#define NBLK ((NEDGES + CHUNK - 1) / CHUNK)     // 391 sort blocks
#define NB ((NNODES + 255) / 256)               // 391 buckets (256 nodes each)
#define FLATN (NB * NBLK)                       // 152881
#define SCB ((FLATN + 255) / 256)               // 598
#define FCAP 5632                               // bucket entry cap (mean 4092, +24 sigma)

typedef __attribute__((ext_vector_type(8))) _Float16 f16x8;
typedef __attribute__((ext_vector_type(2))) _Float16 h2;
typedef __attribute__((ext_vector_type(4))) float f32x4;

__device__ __forceinline__ float wave_sum64(float v) {
#pragma unroll
    for (int off = 1; off < 64; off <<= 1) v += __shfl_xor(v, off, 64);
    return v;
}

__device__ __forceinline__ int wave_sum64i(int v) {
#pragma unroll
    for (int off = 1; off < 64; off <<= 1) v += __shfl_xor(v, off, 64);
    return v;
}

// f32 -> f16 bits (RNE per IEEE conversion semantics)
__device__ __forceinline__ unsigned short f16rne(float a) {
    _Float16 h = (_Float16)a;
    unsigned short u;
    __builtin_memcpy(&u, &h, 2);
    return u;
}

// pack two f32 -> one uint of 2 f16
__device__ __forceinline__ unsigned packh2(float a, float b) {
    h2 v = {(_Float16)a, (_Float16)b};
    unsigned u;
    __builtin_memcpy(&u, &v, 4);
    return u;
}

__device__ __forceinline__ h2 habs(h2 x) {
    unsigned u;
    __builtin_memcpy(&u, &x, 4);
    u &= 0x7FFF7FFFu;
    h2 r;
    __builtin_memcpy(&r, &u, 4);
    return r;
}

// ---------------- phase A: per-chunk counting sort by bucket (all-coalesced) ----------------

__global__ __launch_bounds__(256) void k_lsort(const int* __restrict__ src,
                                               const int* __restrict__ dst,
                                               const float* __restrict__ ea,
                                               uint2* __restrict__ tmps,
                                               int* __restrict__ gcnt,
                                               int* __restrict__ lscan,
                                               float* __restrict__ easum) {
    __shared__ uint2 ent[CHUNK];                 // 32 KB
    __shared__ unsigned short perm[CHUNK];       // 8 KB
    __shared__ int hist[NB];
    __shared__ int cur[NB];
    __shared__ float ws[4];
    const int t = threadIdx.x;
    const int j = blockIdx.x;
    const int base = j * CHUNK;
    const int n = min(CHUNK, NEDGES - base);

    for (int b = t; b < NB; b += 256) hist[b] = 0;
    __syncthreads();

    int bkt[EPT];
    float s = 0.f;
#pragma unroll
    for (int k = 0; k < EPT; ++k) {
        const int l = t + k * 256;
        bkt[k] = -1;
        if (l < n) {
            const int i = base + l;
            const int d = dst[i];
            const float e = ea[i];
            const int b = d >> 8;
            bkt[k] = b;
            ent[l] = make_uint2((unsigned)src[i] | ((unsigned)(d & 255) << 17),
                                __float_as_uint(e));
            atomicAdd(&hist[b], 1);
            s += e;
        }
    }
    s = wave_sum64(s);
    if ((t & 63) == 0) ws[t >> 6] = s;
    __syncthreads();
    if (t == 0) atomicAdd(easum, ws[0] + ws[1] + ws[2] + ws[3]);

    // exclusive scan of hist[0..NB) -> cur, wave 0 only (56 lanes x 7 elems)
    if (t < 64) {
        int x[7];
        int run = 0;
#pragma unroll
        for (int q = 0; q < 7; ++q) {
            const int idx = t * 7 + q;
            x[q] = (idx < NB) ? hist[idx] : 0;
            run += x[q];
        }
        int inc = run;
#pragma unroll
        for (int o = 1; o < 64; o <<= 1) {
            int u = __shfl_up(inc, o, 64);
            if (t >= o) inc += u;
        }
        int r = inc - run;   // lane-exclusive
#pragma unroll
        for (int q = 0; q < 7; ++q) {
            const int idx = t * 7 + q;
            if (idx < NB) cur[idx] = r;
            r += x[q];
        }
    }
    __syncthreads();

#pragma unroll
    for (int k = 0; k < EPT; ++k) {
        if (bkt[k] >= 0) {
            const int r = atomicAdd(&cur[bkt[k]], 1);
            perm[r] = (unsigned short)(t + k * 256);
        }
    }
    __syncthreads();

    for (int o = t; o < n; o += 256)
        tmps[base + o] = ent[perm[o]];           // coalesced global write
    for (int b = t; b < NB; b += 256) {
        gcnt[b * NBLK + j] = hist[b];            // bucket-major (for flat scan)
        lscan[j * NB + b] = cur[b] - hist[b];    // local exclusive offset
    }
}

// ---------------- flat exclusive scan of gcnt[FLATN] -> goff ----------------

__global__ __launch_bounds__(256) void k_part2(const int* __restrict__ v, int n,
                                               int* __restrict__ bsum) {
    int i = blockIdx.x * 256 + threadIdx.x;
    int x = (i < n) ? v[i] : 0;
    x = wave_sum64i(x);
    __shared__ int wsh[4];
    if ((threadIdx.x & 63) == 0) wsh[threadIdx.x >> 6] = x;
    __syncthreads();
    if (threadIdx.x == 0) bsum[blockIdx.x] = wsh[0] + wsh[1] + wsh[2] + wsh[3];
}

__global__ __launch_bounds__(1024) void k_scanb2(const int* __restrict__ bsum, int nb,
                                                 int* __restrict__ boff,
                                                 int* __restrict__ rowptr) {
    __shared__ int sh[1024];
    int t = threadIdx.x;
    int v = (t < nb) ? bsum[t] : 0;
    sh[t] = v;
    __syncthreads();
    for (int off = 1; off < 1024; off <<= 1) {
        int u = (t >= off) ? sh[t - off] : 0;
        __syncthreads();
        sh[t] += u;
        __syncthreads();
    }
    if (t < nb) boff[t] = sh[t] - v;
    if (t == 0) rowptr[NNODES] = NEDGES;
}

__global__ __launch_bounds__(256) void k_scanfin2(const int* __restrict__ v, int n,
                                                  const int* __restrict__ boff,
                                                  int* __restrict__ out) {
    int t = threadIdx.x, lane = t & 63, wave = t >> 6;
    int i = blockIdx.x * 256 + t;
    int x = (i < n) ? v[i] : 0;
    int orig = x;
#pragma unroll
    for (int off = 1; off < 64; off <<= 1) {
        int u = __shfl_up(x, off, 64);
        if (lane >= off) x += u;
    }
    __shared__ int wsh[4];
    if (lane == 63) wsh[wave] = x;
    __syncthreads();
    int wexc = 0;
    for (int w = 0; w < wave; ++w) wexc += wsh[w];
    if (i < n) out[i] = boff[blockIdx.x] + wexc + x - orig;
}

// ---------------- phase C: per-bucket gather + LDS counting sort by node ----------------

__global__ __launch_bounds__(256) void k_fsort(const uint2* __restrict__ tmps,
                                               const int* __restrict__ lscan,
                                               const int* __restrict__ goff,
                                               int* __restrict__ rowptr,
                                               uint2* __restrict__ edata) {
    __shared__ uint2 ent[FCAP];                  // 44 KB
    __shared__ unsigned short perm[FCAP];        // 11 KB
    __shared__ int joff[NBLK + 1];
    __shared__ int jsrc[NBLK];
    __shared__ int hist[256];
    __shared__ int cur[256];
    const int b = blockIdx.x;
    const int t = threadIdx.x;
    const int base = goff[b * NBLK];             // bucket base position in edata

    for (int q = t; q < 256; q += 256) hist[q] = 0;
    for (int j = t; j < NBLK; j += 256) {
        joff[j] = goff[b * NBLK + j] - base;
        jsrc[j] = j * CHUNK + lscan[j * NB + b];
    }
    if (t == 0) joff[NBLK] = ((b == NB - 1) ? NEDGES : goff[(b + 1) * NBLK]) - base;
    __syncthreads();
    const int T = min(joff[NBLK], FCAP);

    for (int idx = t; idx < T; idx += 256) {
        int lo = 0, hi = NBLK;
        while (hi - lo > 1) { int mid = (lo + hi) >> 1; if (joff[mid] <= idx) lo = mid; else hi = mid; }
        const uint2 e = tmps[jsrc[lo] + (idx - joff[lo])];   // piecewise-coalesced
        ent[idx] = e;
        atomicAdd(&hist[(e.x >> 17) & 255u], 1);
    }
    __syncthreads();

    // exclusive scan hist[0..256) -> cur, wave 0 (64 lanes x 4)
    if (t < 64) {
        int x[4];
        int run = 0;
#pragma unroll
        for (int q = 0; q < 4; ++q) { x[q] = hist[t * 4 + q]; run += x[q]; }
        int inc = run;
#pragma unroll
        for (int o = 1; o < 64; o <<= 1) {
            int u = __shfl_up(inc, o, 64);
            if (t >= o) inc += u;
        }
        int r = inc - run;
#pragma unroll
        for (int q = 0; q < 4; ++q) { cur[t * 4 + q] = r; r += x[q]; }
    }
    __syncthreads();

    {
        const int i = b * 256 + t;
        if (i < NNODES) rowptr[i] = base + cur[t];
    }
    __syncthreads();    // rowptr reads of cur must complete before rank mutation

    for (int idx = t; idx < T; idx += 256) {
        const int d = (int)((ent[idx].x >> 17) & 255u);
        const int r = atomicAdd(&cur[d], 1);
        perm[r] = (unsigned short)idx;
    }
    __syncthreads();
    for (int k = t; k < T; k += 256)
        edata[base + k] = ent[perm[k]];          // coalesced global write
}

// ---------------- weight/param pre-conversion ----------------
// Wt*: f32 [K][64] x2 -> f16 col-major [128][K] for MFMA staging.
// epar: per layer 96 dwords = h2 We[32] | h2 0.6*att[32] | h2 0.4*att[32].

__global__ __launch_bounds__(256) void k_wprep(const float* __restrict__ W1l, const float* __restrict__ W1r,
                                               const float* __restrict__ W2l, const float* __restrict__ W2r,
                                               const float* __restrict__ W3l, const float* __restrict__ W3r,
                                               const float* __restrict__ We1, const float* __restrict__ att1,
                                               const float* __restrict__ We2, const float* __restrict__ att2,
                                               const float* __restrict__ We3, const float* __restrict__ att3,
                                               unsigned short* __restrict__ Wt1,
                                               unsigned short* __restrict__ Wt2,
                                               unsigned short* __restrict__ Wt3,
                                               unsigned* __restrict__ epar) {
    const int idx = blockIdx.x * 256 + threadIdx.x;
    if (idx < 16384) {                            // Wt1: 128 cols x 128 k
        const int c = idx >> 7, k = idx & 127;
        const float v = (c < 64) ? W1l[k * 64 + c] : W1r[k * 64 + (c - 64)];
        Wt1[c * 128 + k] = f16rne(v);
    } else if (idx < 24576) {                     // Wt2: 128 cols x 64 k
        const int j = idx - 16384;
        const int c = j >> 6, k = j & 63;
        const float v = (c < 64) ? W2l[k * 64 + c] : W2r[k * 64 + (c - 64)];
        Wt2[c * 64 + k] = f16rne(v);
    } else if (idx < 32768) {                     // Wt3: 128 cols x 64 k
        const int j = idx - 24576;
        const int c = j >> 6, k = j & 63;
        const float v = (c < 64) ? W3l[k * 64 + c] : W3r[k * 64 + (c - 64)];
        Wt3[c * 64 + k] = f16rne(v);
    } else if (idx < 32768 + 288) {               // epar: 3 layers x 3 arrays x 32 h2
        const int j = idx - 32768;
        const int layer = j / 96, rem = j % 96;
        const int arr = rem >> 5, q = rem & 31;
        const float* We = (layer == 0) ? We1 : (layer == 1) ? We2 : We3;
        const float* at = (layer == 0) ? att1 : (layer == 1) ? att2 : att3;
        float a, b;
        if (arr == 0)      { a = We[2 * q];          b = We[2 * q + 1]; }
        else if (arr == 1) { a = 0.6f * at[2 * q];   b = 0.6f * at[2 * q + 1]; }
        else               { a = 0.4f * at[2 * q];   b = 0.4f * at[2 * q + 1]; }
        epar[layer * 96 + arr * 32 + q] = packh2(a, b);
    }
}

// ---------------- MFMA dual GEMM: [XL|XR] = X @ [Wl|Wr] + bias, f16 in/out ----------------

template <int K, bool F32IN>
__global__ __launch_bounds__(256) void k_gemm_mfma(const void* __restrict__ Xin,
                                                   const unsigned short* __restrict__ Wt,
                                                   const float* __restrict__ bl,
                                                   const float* __restrict__ br,
                                                   unsigned short* __restrict__ XLu,
                                                   unsigned short* __restrict__ XRu) {
    constexpr int KP = K + 8;
    __shared__ unsigned short sA[64 * KP];
    __shared__ unsigned short sB[128 * KP];
    const int t = threadIdx.x;
    const int w = t >> 6, lane = t & 63;
    const int r0 = blockIdx.x * 64;

    {
        const uint4* Wu = (const uint4*)Wt;
#pragma unroll
        for (int idx = t; idx < 128 * (K / 8); idx += 256) {
            const int row = idx / (K / 8), q = idx % (K / 8);
            *(uint4*)&sB[row * KP + q * 8] = Wu[idx];
        }
    }
    if constexpr (F32IN) {
        const float* X = (const float*)Xin;
        for (int idx = t; idx < 64 * (K / 4); idx += 256) {
            const int row = idx / (K / 4), q = idx % (K / 4);
            const int rr = min(r0 + row, NNODES - 1);
            const float4 v = *(const float4*)&X[(size_t)rr * K + q * 4];
            unsigned* p = (unsigned*)&sA[row * KP + q * 4];
            p[0] = packh2(v.x, v.y);
            p[1] = packh2(v.z, v.w);
        }
    } else {
        const uint4* X = (const uint4*)Xin;      // packed f16 rows: 8 x uint4
        for (int idx = t; idx < 64 * 8; idx += 256) {
            const int row = idx >> 3, q = idx & 7;
            const int rr = min(r0 + row, NNODES - 1);
            *(uint4*)&sA[row * KP + q * 8] = X[(size_t)rr * 8 + q];
        }
    }
    __syncthreads();

    f32x4 acc[8] = {};
    const int mrow = w * 16 + (lane & 15);
    const int kb = (lane >> 4) * 8;
#pragma unroll
    for (int kc = 0; kc < K / 32; ++kc) {
        const f16x8 af = *(const f16x8*)&sA[mrow * KP + kc * 32 + kb];
#pragma unroll
        for (int nt = 0; nt < 8; ++nt) {
            const f16x8 bfr = *(const f16x8*)&sB[(nt * 16 + (lane & 15)) * KP + kc * 32 + kb];
            acc[nt] = __builtin_amdgcn_mfma_f32_16x16x32_f16(af, bfr, acc[nt], 0, 0, 0);
        }
    }

    const int colL = lane & 15;
    const int rbase = r0 + w * 16 + (lane >> 4) * 4;
#pragma unroll
    for (int nt = 0; nt < 8; ++nt) {
        const int col = nt * 16 + colL;
        const bool isL = col < 64;
        const float bv = isL ? bl[col] : br[col - 64];
        unsigned short* OUT = isL ? XLu : XRu;
        const int oc = isL ? col : col - 64;
#pragma unroll
        for (int r = 0; r < 4; ++r) {
            const int grow = rbase + r;
            if (grow < NNODES)
                OUT[(size_t)grow * 64 + oc] = f16rne(acc[nt][r] + bv);
        }
    }
}

// ---------------- fused GATv2 edge pass (packed-f16, 1 node per wave, epar consts) ----------------
// One wave per node (max TLP: 100K independent waves). lane = 8*group + fl;
// group g handles edge e+g (8/batch); lane holds features [fl*8,fl*8+8) as
// 4x h2 from one uint4. Constants via pre-packed epar (3 uint4 loads).
// Fixed-base softmax (C = self logit). Per-wave LDS combine, no block barrier.

__global__ __launch_bounds__(256) void k_edge(const uint4* __restrict__ XLh,
                                              const uint4* __restrict__ XRh,
                                              const int* __restrict__ rowptr,
                                              const uint2* __restrict__ edata,
                                              const unsigned* __restrict__ epar,
                                              const float* __restrict__ bias,
                                              const float* __restrict__ easum,
                                              unsigned* __restrict__ Hh) {
    __shared__ float red[4][8][65];              // bank = (g + 8*fl + k) % 32: 2/bank (free)
    const int wave = threadIdx.x >> 6, lane = threadIdx.x & 63;
    const int g = lane >> 3, fl = lane & 7;
    const int fo = fl * 8;

    h2 We2[4], a06[4], a04[4];
    {
        const uint4 wu = ((const uint4*)epar)[fl];
        const uint4 u6 = ((const uint4*)(epar + 32))[fl];
        const uint4 u4 = ((const uint4*)(epar + 64))[fl];
        __builtin_memcpy(We2, &wu, 16);
        __builtin_memcpy(a06, &u6, 16);
        __builtin_memcpy(a04, &u4, 16);
    }
    const float bias_l = bias[lane];
    const float ea_mean = easum[0] * (1.0f / NEDGES);
    const _Float16 eh_mean = (_Float16)ea_mean;
    const h2 evm = h2{eh_mean, eh_mean};
    const uint2 z2 = make_uint2(0u, 0u);

    const int i = blockIdx.x * 4 + wave;         // exact grid: always < NNODES

    h2 xr2[4], xl2[4];
    {
        const uint4 wr = XRh[(size_t)i * 8 + fl];
        __builtin_memcpy(xr2, &wr, 16);
        const uint4 wl = XLh[(size_t)i * 8 + fl];
        __builtin_memcpy(xl2, &wl, 16);
    }

    // self-loop logit: identical across groups -> wave-uniform after reduce
    float M;
    {
        h2 s1v = h2{(_Float16)0.f, (_Float16)0.f};
        h2 s2v = s1v;
#pragma unroll
        for (int k = 0; k < 4; ++k) {
            const h2 m = __builtin_elementwise_fma(evm, We2[k], xr2[k]) + xl2[k];
            s1v = __builtin_elementwise_fma(a06[k], m, s1v);
            s2v = __builtin_elementwise_fma(a04[k], habs(m), s2v);
        }
        const h2 sv = s1v + s2v;
        float pt = (float)sv[0] + (float)sv[1];
        pt += __shfl_xor(pt, 1);
        pt += __shfl_xor(pt, 2);
        pt += __shfl_xor(pt, 4);
        M = pt;                                  // fixed softmax base
    }
    float S = (g == 0) ? 1.f : 0.f;              // self-loop: exp(M-M)=1, group 0 only
    float acc8[8];
#pragma unroll
    for (int k = 0; k < 4; ++k) {
        acc8[2 * k] = (g == 0) ? (float)xl2[k][0] : 0.f;
        acc8[2 * k + 1] = (g == 0) ? (float)xl2[k][1] : 0.f;
    }

    const int e0 = rowptr[i];
    const int ne = rowptr[i + 1] - e0;

    uint2 se = (g < ne) ? edata[e0 + g] : z2;    // meta prefetch, 1 batch ahead
    for (int e = 0; e < ne; e += 8) {
        const uint2 se_cur = se;
        const bool valid = (e + g) < ne;
        if (e + 8 + g < ne) se = edata[e0 + e + 8 + g];
        const int s = (int)(se_cur.x & 0x1FFFFu);
        const float eav = __uint_as_float(se_cur.y);
        const uint4 wv = XLh[(size_t)s * 8 + fl];
        h2 v2[4];
        __builtin_memcpy(v2, &wv, 16);
        const _Float16 eh = (_Float16)eav;
        const h2 ev2 = h2{eh, eh};

        h2 s1v = h2{(_Float16)0.f, (_Float16)0.f};
        h2 s2v = s1v;
#pragma unroll
        for (int k = 0; k < 4; ++k) {
            const h2 m = __builtin_elementwise_fma(ev2, We2[k], xr2[k]) + v2[k];
            s1v = __builtin_elementwise_fma(a06[k], m, s1v);
            s2v = __builtin_elementwise_fma(a04[k], habs(m), s2v);
        }
        const h2 sv = s1v + s2v;
        float d = (float)sv[0] + (float)sv[1];
        d += __shfl_xor(d, 1);
        d += __shfl_xor(d, 2);
        d += __shfl_xor(d, 4);                   // group-uniform logit
        const float a = valid ? d : -1e30f;      // exp(-inf)=0 for pad groups

        const float p = __expf(a - M);           // fixed base: no max tracking
        S += p;                                  // group-partial (deferred reduce)
#pragma unroll
        for (int k = 0; k < 4; ++k) {
            acc8[2 * k] = fmaf(p, (float)v2[k][0], acc8[2 * k]);
            acc8[2 * k + 1] = fmaf(p, (float)v2[k][1], acc8[2 * k + 1]);
        }
    }

    // reduce S across groups (xor 8/16/32 touches g bits only)
    S += __shfl_xor(S, 8);
    S += __shfl_xor(S, 16);
    S += __shfl_xor(S, 32);

    // per-wave LDS transpose-combine (no inter-wave sharing -> no block barrier)
#pragma unroll
    for (int k = 0; k < 8; ++k) red[wave][g][fo + k] = acc8[k];
    asm volatile("" ::: "memory");
    __builtin_amdgcn_wave_barrier();             // DS ops complete in-order per wave
    float o = 0.f;
#pragma unroll
    for (int gg = 0; gg < 8; ++gg) o += red[wave][gg][lane];
    o = fmaxf(o / S + bias_l, 0.f);              // bias + fused ReLU
    const float on = __shfl_xor(o, 1);
    if (!(lane & 1))
        Hh[(size_t)i * 32 + (lane >> 1)] = packh2(o, on);   // packed f16 store
}

// ---------------- tail: mean pool + linear + softmax ----------------

__global__ __launch_bounds__(256) void k_colsum(const unsigned* __restrict__ Hh,
                                                float* __restrict__ gsum) {
    const int t = threadIdx.x;
    const int c = t & 31;                        // uint column = feature pair
    const int rl = t >> 5;                       // 0..7
    float s0 = 0.f, s1 = 0.f;
    for (int r = blockIdx.x * 8 + rl; r < NNODES; r += gridDim.x * 8) {
        const unsigned u = Hh[(size_t)r * 32 + c];
        h2 hv;
        __builtin_memcpy(&hv, &u, 4);
        s0 += (float)hv[0];
        s1 += (float)hv[1];
    }
    __shared__ float ls[8][64];
    ls[rl][2 * c] = s0;
    ls[rl][2 * c + 1] = s1;
    __syncthreads();
    if (t < 64) {
        float s = 0.f;
#pragma unroll
        for (int q = 0; q < 8; ++q) s += ls[q][t];
        atomicAdd(&gsum[t], s);
    }
}

__global__ __launch_bounds__(64) void k_head(const float* __restrict__ gsum,
                                             const float* __restrict__ Wlin,
                                             const float* __restrict__ blin,
                                             float* __restrict__ out) {
    int lane = threadIdx.x;
    float g = gsum[lane] * (1.0f / NNODES);
    float a0 = wave_sum64(g * Wlin[lane * 2 + 0]);
    float a1 = wave_sum64(g * Wlin[lane * 2 + 1]);
    if (lane == 0) {
        float l0 = a0 + blin[0], l1 = a1 + blin[1];
        float mx = fmaxf(l0, l1);
        float e0 = __expf(l0 - mx), e1 = __expf(l1 - mx);
        float inv = 1.f / (e0 + e1);
        out[0] = e0 * inv;
        out[1] = e1 * inv;
    }
}

extern "C" void kernel_launch(void* const* d_in, const int* in_sizes, int n_in,
                              void* d_out, int out_size, void* d_ws, size_t ws_size,
                              hipStream_t stream) {
    const float* x = (const float*)d_in[0];
    const int* ei = (const int*)d_in[1];
    const float* ea = (const float*)d_in[2];
    const int* src = ei;
    const int* dst = ei + NEDGES;
    auto W = [&](int i) { return (const float*)d_in[i]; };

    char* ws = (char*)d_ws;
    size_t off = 0;
    auto alloc = [&](size_t bytes) {
        void* p = ws + off;
        off += (bytes + 255) & ~(size_t)255;
        return p;
    };
    unsigned short* XLu = (unsigned short*)alloc((size_t)NNODES * 64 * 2);  // packed f16
    unsigned short* XRu = (unsigned short*)alloc((size_t)NNODES * 64 * 2);  // packed f16
    unsigned* Hh = (unsigned*)alloc((size_t)NBLK * CHUNK * 8);  // 12.82 MB: packed f16 H, aliased by tmps
    int* rowptr = (int*)alloc((size_t)(NNODES + 1) * 4);
    uint2* edata = (uint2*)alloc((size_t)NEDGES * 8);
    float* easum = (float*)alloc(4);
    float* gsum = (float*)alloc(64 * 4);
    int* gcnt = (int*)alloc((size_t)FLATN * 4);
    int* lscan = (int*)alloc((size_t)FLATN * 4);
    int* goff = (int*)alloc((size_t)FLATN * 4);
    int* part2 = (int*)alloc((size_t)SCB * 4);
    int* boff2 = (int*)alloc((size_t)SCB * 4);
    unsigned short* Wt1 = (unsigned short*)alloc(16384 * 2);
    unsigned short* Wt2 = (unsigned short*)alloc(8192 * 2);
    unsigned short* Wt3 = (unsigned short*)alloc(8192 * 2);
    unsigned* epar = (unsigned*)alloc(288 * 4);  // 3 layers x {We,0.6att,0.4att} h2 packs
    uint2* tmps = (uint2*)Hh;  // Hh dead until layer-1 k_edge; sort uses it first

    hipMemsetAsync(easum, 0, 4, stream);
    hipMemsetAsync(gsum, 0, 64 * 4, stream);

    k_wprep<<<130, 256, 0, stream>>>(W(3), W(5), W(10), W(12), W(17), W(19),
                                     W(7), W(8), W(14), W(15), W(21), W(22),
                                     Wt1, Wt2, Wt3, epar);
    k_lsort<<<NBLK, 256, 0, stream>>>(src, dst, ea, tmps, gcnt, lscan, easum);
    k_part2<<<SCB, 256, 0, stream>>>(gcnt, FLATN, part2);
    k_scanb2<<<1, 1024, 0, stream>>>(part2, SCB, boff2, rowptr);
    k_scanfin2<<<SCB, 256, 0, stream>>>(gcnt, FLATN, boff2, goff);
    k_fsort<<<NB, 256, 0, stream>>>(tmps, lscan, goff, rowptr, edata);

    int gemm_grid = (NNODES + 63) / 64;   // 1563
    int edge_grid = NNODES / 4;           // 25000: one wave per node (max TLP)

    k_gemm_mfma<128, true><<<gemm_grid, 256, 0, stream>>>(x, Wt1, W(4), W(6), XLu, XRu);
    k_edge<<<edge_grid, 256, 0, stream>>>((const uint4*)XLu, (const uint4*)XRu, rowptr, edata,
                                          epar, W(9), easum, Hh);
    k_gemm_mfma<64, false><<<gemm_grid, 256, 0, stream>>>(Hh, Wt2, W(11), W(13), XLu, XRu);
    k_edge<<<edge_grid, 256, 0, stream>>>((const uint4*)XLu, (const uint4*)XRu, rowptr, edata,
                                          epar + 96, W(16), easum, Hh);
    k_gemm_mfma<64, false><<<gemm_grid, 256, 0, stream>>>(Hh, Wt3, W(18), W(20), XLu, XRu);
    k_edge<<<edge_grid, 256, 0, stream>>>((const uint4*)XLu, (const uint4*)XRu, rowptr, edata,
                                          epar + 192, W(23), easum, Hh);

    k_colsum<<<256, 256, 0, stream>>>(Hh, gsum);
    k_head<<<1, 64, 0, stream>>>(gsum, W(24), W(25), (float*)d_out);
}